// Round 1
// baseline (533.787 us; speedup 1.0000x reference)
//
#include <hip/hip_runtime.h>

#define N_NODES 100000
#define N_EDGES 1600000
#define N_REL   16
#define N_BASES 4
#define LN_EPS  1e-5f

// ---------------------------------------------------------------------------
// Kernel 1: hb[n][o][b] = sum_i x[n][i] * bases[b][i][o]
// layout b-innermost so the edge kernel gathers one float4 per lane.
// Each thread t: o = t>>2, b = t&3; preloads bases[b][:, o] into 64 VGPRs.
// x rows are wave-uniform -> scalar loads.
// ---------------------------------------------------------------------------
__global__ __launch_bounds__(256) void k_basis_transform(
    const float* __restrict__ x,      // [N,64]
    const float* __restrict__ bases,  // [4,64,64]
    float* __restrict__ hb)           // [N,64,4]
{
    const int t = threadIdx.x;
    const int o = t >> 2;
    const int b = t & 3;
    float vreg[64];
#pragma unroll
    for (int i = 0; i < 64; ++i)
        vreg[i] = bases[b * 4096 + i * 64 + o];

    for (int n = blockIdx.x; n < N_NODES; n += gridDim.x) {
        const float* xr = x + (size_t)n * 64;
        float acc = 0.f;
#pragma unroll
        for (int i = 0; i < 64; ++i)
            acc = fmaf(xr[i], vreg[i], acc);
        hb[(size_t)n * 256 + t] = acc;
    }
}

// ---------------------------------------------------------------------------
// Kernel 2: one wave per edge. lane = output feature.
// m[o] = dot(comp[et], hb[src][o][0..3]); atomicAdd into agg[dst][o].
// ---------------------------------------------------------------------------
__global__ __launch_bounds__(256) void k_edge_scatter(
    const float4* __restrict__ hb,    // [N,64] of float4
    const float4* __restrict__ comp,  // [16] of float4
    const int* __restrict__ src,
    const int* __restrict__ dst,
    const int* __restrict__ et,
    float* __restrict__ agg)          // [N,64]
{
    const int lane = threadIdx.x & 63;
    int e = blockIdx.x * 4 + (threadIdx.x >> 6);
    if (e >= N_EDGES) return;
    e = __builtin_amdgcn_readfirstlane(e);   // force scalar index loads
    const int s = src[e];
    const int d = dst[e];
    const int r = et[e];
    const float4 c = comp[r];
    const float4 h = hb[(size_t)s * 64 + lane];
    const float m = c.x * h.x + c.y * h.y + c.z * h.z + c.w * h.w;
    atomicAdd(&agg[(size_t)d * 64 + lane], m);
}

// ---------------------------------------------------------------------------
// Fallback A (ws >= 25.6MB): per-basis pass
// ---------------------------------------------------------------------------
__global__ __launch_bounds__(256) void k_basis_one(
    const float* __restrict__ x, const float* __restrict__ bases, int b,
    float* __restrict__ hbb)          // [N,64]
{
    const int lane = threadIdx.x & 63;
    const int wid  = threadIdx.x >> 6;
    float vreg[64];
#pragma unroll
    for (int i = 0; i < 64; ++i)
        vreg[i] = bases[b * 4096 + i * 64 + lane];
    const int waves = gridDim.x * 4;
    for (int n = blockIdx.x * 4 + wid; n < N_NODES; n += waves) {
        const float* xr = x + (size_t)n * 64;
        float acc = 0.f;
#pragma unroll
        for (int i = 0; i < 64; ++i)
            acc = fmaf(xr[i], vreg[i], acc);
        hbb[(size_t)n * 64 + lane] = acc;
    }
}

__global__ __launch_bounds__(256) void k_edge_one(
    const float* __restrict__ hbb, const float* __restrict__ comp, int b,
    const int* __restrict__ src, const int* __restrict__ dst,
    const int* __restrict__ et, float* __restrict__ agg)
{
    const int lane = threadIdx.x & 63;
    int e = blockIdx.x * 4 + (threadIdx.x >> 6);
    if (e >= N_EDGES) return;
    e = __builtin_amdgcn_readfirstlane(e);
    const int s = src[e], d = dst[e], r = et[e];
    const float c = comp[r * 4 + b];
    atomicAdd(&agg[(size_t)d * 64 + lane], c * hbb[(size_t)s * 64 + lane]);
}

// ---------------------------------------------------------------------------
// Fallback B (no ws): direct per-edge compute
// ---------------------------------------------------------------------------
__global__ __launch_bounds__(256) void k_edge_direct(
    const float* __restrict__ x, const float* __restrict__ bases,
    const float* __restrict__ comp,
    const int* __restrict__ src, const int* __restrict__ dst,
    const int* __restrict__ et, float* __restrict__ agg)
{
    const int lane = threadIdx.x & 63;
    int e = blockIdx.x * 4 + (threadIdx.x >> 6);
    if (e >= N_EDGES) return;
    e = __builtin_amdgcn_readfirstlane(e);
    const int s = src[e], d = dst[e], r = et[e];
    const float4 c = *(const float4*)(comp + r * 4);
    const float* xr = x + (size_t)s * 64;
    float acc = 0.f;
    for (int i = 0; i < 64; ++i) {
        const float w = c.x * bases[i * 64 + lane]
                      + c.y * bases[4096 + i * 64 + lane]
                      + c.z * bases[8192 + i * 64 + lane]
                      + c.w * bases[12288 + i * 64 + lane];
        acc = fmaf(xr[i], w, acc);
    }
    atomicAdd(&agg[(size_t)d * 64 + lane], acc);
}

// ---------------------------------------------------------------------------
// Kernel 3: out[n] = LayerNorm(LeakyReLU(agg[n] + x[n]@loopW + bias)) in-place.
// One wave per node; lane = output feature. Wave-wide shfl_xor reductions.
// ---------------------------------------------------------------------------
__global__ __launch_bounds__(256) void k_finalize(
    const float* __restrict__ x,
    const float* __restrict__ loopw,  // [64,64] (i,o)
    const float* __restrict__ bias,
    const float* __restrict__ gamma,
    const float* __restrict__ beta,
    float* __restrict__ out)          // in: agg, out: result
{
    const int lane = threadIdx.x & 63;
    const int wid  = threadIdx.x >> 6;
    float wreg[64];
#pragma unroll
    for (int i = 0; i < 64; ++i)
        wreg[i] = loopw[i * 64 + lane];
    const float bs = bias[lane], gm = gamma[lane], bt = beta[lane];
    const int waves = gridDim.x * 4;
    for (int n = blockIdx.x * 4 + wid; n < N_NODES; n += waves) {
        const float* xr = x + (size_t)n * 64;
        float acc = 0.f;
#pragma unroll
        for (int i = 0; i < 64; ++i)
            acc = fmaf(xr[i], wreg[i], acc);
        float v = out[(size_t)n * 64 + lane] + acc + bs;
        v = (v >= 0.f) ? v : 0.1f * v;
        // mean
        float s1 = v;
#pragma unroll
        for (int m = 32; m >= 1; m >>= 1) s1 += __shfl_xor(s1, m, 64);
        const float mu = s1 * (1.f / 64.f);
        // variance (two-pass for accuracy)
        const float dv = v - mu;
        float s2 = dv * dv;
#pragma unroll
        for (int m = 32; m >= 1; m >>= 1) s2 += __shfl_xor(s2, m, 64);
        const float var = s2 * (1.f / 64.f);
        out[(size_t)n * 64 + lane] = dv * rsqrtf(var + LN_EPS) * gm + bt;
    }
}

// ---------------------------------------------------------------------------
extern "C" void kernel_launch(void* const* d_in, const int* in_sizes, int n_in,
                              void* d_out, int out_size, void* d_ws, size_t ws_size,
                              hipStream_t stream) {
    const float* x     = (const float*)d_in[0];
    const float* bases = (const float*)d_in[1];
    const float* comp  = (const float*)d_in[2];
    const float* loopw = (const float*)d_in[3];
    const float* bias  = (const float*)d_in[4];
    const float* gamma = (const float*)d_in[5];
    const float* beta  = (const float*)d_in[6];
    const int*   src   = (const int*)d_in[7];
    const int*   dst   = (const int*)d_in[8];
    const int*   et    = (const int*)d_in[9];
    float* out = (float*)d_out;

    // agg lives in d_out; zero it each call (harness does not re-poison).
    hipMemsetAsync(d_out, 0, (size_t)N_NODES * 64 * sizeof(float), stream);

    const int edge_blocks = (N_EDGES + 3) / 4;
    const size_t need_full = (size_t)N_NODES * 256 * sizeof(float);  // 102.4 MB
    const size_t need_one  = (size_t)N_NODES * 64 * sizeof(float);   // 25.6 MB

    if (ws_size >= need_full) {
        float* hb = (float*)d_ws;
        k_basis_transform<<<2048, 256, 0, stream>>>(x, bases, hb);
        k_edge_scatter<<<edge_blocks, 256, 0, stream>>>(
            (const float4*)hb, (const float4*)comp, src, dst, et, out);
    } else if (ws_size >= need_one) {
        float* hbb = (float*)d_ws;
        for (int b = 0; b < N_BASES; ++b) {
            k_basis_one<<<2048, 256, 0, stream>>>(x, bases, b, hbb);
            k_edge_one<<<edge_blocks, 256, 0, stream>>>(hbb, comp, b, src, dst, et, out);
        }
    } else {
        k_edge_direct<<<edge_blocks, 256, 0, stream>>>(x, bases, comp, src, dst, et, out);
    }

    k_finalize<<<2048, 256, 0, stream>>>(x, loopw, bias, gamma, beta, out);
}

// Round 2
// 493.170 us; speedup vs baseline: 1.0824x; 1.0824x over previous
//
#include <hip/hip_runtime.h>

#define N_NODES 100000
#define N_EDGES 1600000
#define NBINS   100000
#define LN_EPS  1e-5f

typedef unsigned int u32;
typedef unsigned short u16;

__device__ __forceinline__ u16 f2bf(float f) {
    u32 u = __float_as_uint(f);
    u32 r = (u + 0x7FFFu + ((u >> 16) & 1u)) >> 16;   // round-to-nearest-even
    return (u16)r;
}
__device__ __forceinline__ float bf2f(u16 h) {
    return __uint_as_float((u32)h << 16);
}

// ---------------------------------------------------------------------------
// hb[n][o][b] = sum_i x[n][i] * bases[b][i][o], stored bf16, b innermost.
// thread t: o = t>>2, b = t&3. One node per block-iteration; x loads uniform.
// ---------------------------------------------------------------------------
__global__ __launch_bounds__(256) void k_basis(
    const float* __restrict__ x, const float* __restrict__ bases,
    u16* __restrict__ hb)
{
    const int t = threadIdx.x;
    const int o = t >> 2;
    const int b = t & 3;
    float vreg[64];
#pragma unroll
    for (int i = 0; i < 64; ++i)
        vreg[i] = bases[b * 4096 + i * 64 + o];
    for (int n = blockIdx.x; n < N_NODES; n += gridDim.x) {
        const float* xr = x + (size_t)n * 64;
        float acc = 0.f;
#pragma unroll
        for (int i = 0; i < 64; ++i)
            acc = fmaf(xr[i], vreg[i], acc);
        hb[(size_t)n * 256 + t] = f2bf(acc);
    }
}

// ---------------------------------------------------------------------------
// Counting sort of edges by dst: histogram -> 2-level scan -> scatter packed.
// ---------------------------------------------------------------------------
__global__ __launch_bounds__(256) void k_hist(
    const int* __restrict__ dst, u32* __restrict__ counts)
{
    int e = blockIdx.x * 256 + threadIdx.x;
    if (e < N_EDGES) atomicAdd(&counts[dst[e]], 1u);
}

__global__ __launch_bounds__(1024) void k_scan_block(
    const u32* __restrict__ counts, u32* __restrict__ offs,
    u32* __restrict__ bsums)
{
    __shared__ u32 s[1024];
    const int t = threadIdx.x;
    const int idx = blockIdx.x * 1024 + t;
    u32 v = (idx < NBINS) ? counts[idx] : 0u;
    s[t] = v;
    __syncthreads();
#pragma unroll
    for (int off = 1; off < 1024; off <<= 1) {
        u32 xv = (t >= off) ? s[t - off] : 0u;
        __syncthreads();
        s[t] += xv;
        __syncthreads();
    }
    if (idx < NBINS) offs[idx] = s[t] - v;      // exclusive
    if (t == 1023) bsums[blockIdx.x] = s[t];    // block total
}

__global__ __launch_bounds__(128) void k_scan_sums(
    const u32* __restrict__ bsums, u32* __restrict__ boffs, int nb)
{
    __shared__ u32 s[128];
    const int t = threadIdx.x;
    u32 v = (t < nb) ? bsums[t] : 0u;
    s[t] = v;
    __syncthreads();
#pragma unroll
    for (int off = 1; off < 128; off <<= 1) {
        u32 xv = (t >= off) ? s[t - off] : 0u;
        __syncthreads();
        s[t] += xv;
        __syncthreads();
    }
    boffs[t] = s[t] - v;                         // exclusive block offsets
}

__global__ __launch_bounds__(256) void k_scatter(
    const int* __restrict__ src, const int* __restrict__ dst,
    const int* __restrict__ et,
    const u32* __restrict__ offs, const u32* __restrict__ boffs,
    u32* __restrict__ cursor, u32* __restrict__ packed)
{
    int e = blockIdx.x * 256 + threadIdx.x;
    if (e >= N_EDGES) return;
    const int d = dst[e];
    u32 pos = offs[d] + boffs[d >> 10] + atomicAdd(&cursor[d], 1u);
    packed[pos] = (u32)src[e] | ((u32)et[e] << 20);
}

// ---------------------------------------------------------------------------
// One wave per dst node: register-accumulate its edge segment (bf16 hb gather,
// 8 B/lane/edge), then fused self-loop + bias + LeakyReLU + LayerNorm.
// ---------------------------------------------------------------------------
__global__ __launch_bounds__(256) void k_agg_final(
    const u16* __restrict__ hb, const float4* __restrict__ comp,
    const u32* __restrict__ packed,
    const u32* __restrict__ offs, const u32* __restrict__ boffs,
    const u32* __restrict__ counts,
    const float* __restrict__ x, const float* __restrict__ loopw,
    const float* __restrict__ bias, const float* __restrict__ gamma,
    const float* __restrict__ beta, float* __restrict__ out)
{
    const int lane = threadIdx.x & 63;
    const int wid = threadIdx.x >> 6;
    float wreg[64];
#pragma unroll
    for (int i = 0; i < 64; ++i)
        wreg[i] = loopw[i * 64 + lane];
    const float bs = bias[lane], gm = gamma[lane], bt = beta[lane];
    const int waves = gridDim.x * 4;
    for (int n = blockIdx.x * 4 + wid; n < N_NODES; n += waves) {
        u32 base = offs[n] + boffs[n >> 10];
        base = __builtin_amdgcn_readfirstlane(base);
        u32 deg = __builtin_amdgcn_readfirstlane(counts[n]);
        float acc = 0.f;
        for (u32 k = 0; k < deg; ++k) {
            u32 rec = __builtin_amdgcn_readfirstlane(packed[base + k]);
            const int s = (int)(rec & 0xFFFFFu);
            const int r = (int)(rec >> 20);
            const float4 c = comp[r];
            const ushort4 hv =
                *(const ushort4*)(hb + (size_t)s * 256 + lane * 4);
            acc += c.x * bf2f(hv.x) + c.y * bf2f(hv.y) +
                   c.z * bf2f(hv.z) + c.w * bf2f(hv.w);
        }
        // self-loop
        const float* xr = x + (size_t)n * 64;
        float sl = 0.f;
#pragma unroll
        for (int i = 0; i < 64; ++i)
            sl = fmaf(xr[i], wreg[i], sl);
        float v = acc + sl + bs;
        v = (v >= 0.f) ? v : 0.1f * v;
        float s1 = v;
#pragma unroll
        for (int m = 32; m >= 1; m >>= 1) s1 += __shfl_xor(s1, m, 64);
        const float mu = s1 * (1.f / 64.f);
        const float dv = v - mu;
        float s2 = dv * dv;
#pragma unroll
        for (int m = 32; m >= 1; m >>= 1) s2 += __shfl_xor(s2, m, 64);
        const float var = s2 * (1.f / 64.f);
        out[(size_t)n * 64 + lane] = dv * rsqrtf(var + LN_EPS) * gm + bt;
    }
}

// ---------------------------------------------------------------------------
// Fallback (tiny ws): direct per-edge compute with atomics + separate finalize.
// ---------------------------------------------------------------------------
__global__ __launch_bounds__(256) void k_edge_direct(
    const float* __restrict__ x, const float* __restrict__ bases,
    const float* __restrict__ comp,
    const int* __restrict__ src, const int* __restrict__ dst,
    const int* __restrict__ et, float* __restrict__ agg)
{
    const int lane = threadIdx.x & 63;
    int e = blockIdx.x * 4 + (threadIdx.x >> 6);
    if (e >= N_EDGES) return;
    e = __builtin_amdgcn_readfirstlane(e);
    const int s = src[e], d = dst[e], r = et[e];
    const float4 c = *(const float4*)(comp + r * 4);
    const float* xr = x + (size_t)s * 64;
    float acc = 0.f;
    for (int i = 0; i < 64; ++i) {
        const float w = c.x * bases[i * 64 + lane]
                      + c.y * bases[4096 + i * 64 + lane]
                      + c.z * bases[8192 + i * 64 + lane]
                      + c.w * bases[12288 + i * 64 + lane];
        acc = fmaf(xr[i], w, acc);
    }
    atomicAdd(&agg[(size_t)d * 64 + lane], acc);
}

__global__ __launch_bounds__(256) void k_finalize(
    const float* __restrict__ x, const float* __restrict__ loopw,
    const float* __restrict__ bias, const float* __restrict__ gamma,
    const float* __restrict__ beta, float* __restrict__ out)
{
    const int lane = threadIdx.x & 63;
    const int wid = threadIdx.x >> 6;
    float wreg[64];
#pragma unroll
    for (int i = 0; i < 64; ++i)
        wreg[i] = loopw[i * 64 + lane];
    const float bs = bias[lane], gm = gamma[lane], bt = beta[lane];
    const int waves = gridDim.x * 4;
    for (int n = blockIdx.x * 4 + wid; n < N_NODES; n += waves) {
        const float* xr = x + (size_t)n * 64;
        float sl = 0.f;
#pragma unroll
        for (int i = 0; i < 64; ++i)
            sl = fmaf(xr[i], wreg[i], sl);
        float v = out[(size_t)n * 64 + lane] + sl + bs;
        v = (v >= 0.f) ? v : 0.1f * v;
        float s1 = v;
#pragma unroll
        for (int m = 32; m >= 1; m >>= 1) s1 += __shfl_xor(s1, m, 64);
        const float mu = s1 * (1.f / 64.f);
        const float dv = v - mu;
        float s2 = dv * dv;
#pragma unroll
        for (int m = 32; m >= 1; m >>= 1) s2 += __shfl_xor(s2, m, 64);
        const float var = s2 * (1.f / 64.f);
        out[(size_t)n * 64 + lane] = dv * rsqrtf(var + LN_EPS) * gm + bt;
    }
}

// ---------------------------------------------------------------------------
extern "C" void kernel_launch(void* const* d_in, const int* in_sizes, int n_in,
                              void* d_out, int out_size, void* d_ws, size_t ws_size,
                              hipStream_t stream) {
    const float* x     = (const float*)d_in[0];
    const float* bases = (const float*)d_in[1];
    const float* comp  = (const float*)d_in[2];
    const float* loopw = (const float*)d_in[3];
    const float* bias  = (const float*)d_in[4];
    const float* gamma = (const float*)d_in[5];
    const float* beta  = (const float*)d_in[6];
    const int*   src   = (const int*)d_in[7];
    const int*   dst   = (const int*)d_in[8];
    const int*   et    = (const int*)d_in[9];
    float* out = (float*)d_out;

    // ws layout (256B-aligned slabs)
    size_t p = 0;
    auto alloc = [&](size_t bytes) {
        size_t cur = p;
        p = (p + bytes + 255) & ~(size_t)255;
        return cur;
    };
    char* ws = (char*)d_ws;
    const size_t o_hb     = alloc((size_t)N_NODES * 256 * sizeof(u16)); // 51.2 MB
    const size_t o_counts = alloc((size_t)NBINS * sizeof(u32));
    const size_t o_offs   = alloc((size_t)NBINS * sizeof(u32));
    const size_t o_cursor = alloc((size_t)NBINS * sizeof(u32));
    const size_t o_bsums  = alloc(128 * sizeof(u32));
    const size_t o_boffs  = alloc(128 * sizeof(u32));
    const size_t o_packed = alloc((size_t)N_EDGES * sizeof(u32));       // 6.4 MB
    const size_t need = p;

    const int edge_blocks = (N_EDGES + 255) / 256;

    if (ws_size >= need) {
        u16* hb     = (u16*)(ws + o_hb);
        u32* counts = (u32*)(ws + o_counts);
        u32* offs   = (u32*)(ws + o_offs);
        u32* cursor = (u32*)(ws + o_cursor);
        u32* bsums  = (u32*)(ws + o_bsums);
        u32* boffs  = (u32*)(ws + o_boffs);
        u32* packed = (u32*)(ws + o_packed);

        hipMemsetAsync(counts, 0, (size_t)NBINS * sizeof(u32), stream);
        hipMemsetAsync(cursor, 0, (size_t)NBINS * sizeof(u32), stream);

        k_basis<<<2048, 256, 0, stream>>>(x, bases, hb);
        k_hist<<<edge_blocks, 256, 0, stream>>>(dst, counts);
        const int scan_blocks = (NBINS + 1023) / 1024;  // 98
        k_scan_block<<<scan_blocks, 1024, 0, stream>>>(counts, offs, bsums);
        k_scan_sums<<<1, 128, 0, stream>>>(bsums, boffs, scan_blocks);
        k_scatter<<<edge_blocks, 256, 0, stream>>>(src, dst, et, offs, boffs,
                                                   cursor, packed);
        k_agg_final<<<2048, 256, 0, stream>>>(hb, (const float4*)comp, packed,
                                              offs, boffs, counts, x, loopw,
                                              bias, gamma, beta, out);
    } else {
        hipMemsetAsync(d_out, 0, (size_t)N_NODES * 64 * sizeof(float), stream);
        k_edge_direct<<<(N_EDGES + 3) / 4, 256, 0, stream>>>(
            x, bases, comp, src, dst, et, out);
        k_finalize<<<2048, 256, 0, stream>>>(x, loopw, bias, gamma, beta, out);
    }
}

// Round 3
// 402.208 us; speedup vs baseline: 1.3271x; 1.2262x over previous
//
#include <hip/hip_runtime.h>

#define N_NODES 100000
#define N_EDGES 1600000
#define NBINS   100000
#define LN_EPS  1e-5f

#define BASIS_BLOCKS 2048
#define HIST_BLOCKS  1024

typedef unsigned int u32;
typedef unsigned short u16;

__device__ __forceinline__ u16 f2bf(float f) {
    u32 u = __float_as_uint(f);
    u32 r = (u + 0x7FFFu + ((u >> 16) & 1u)) >> 16;   // round-to-nearest-even
    return (u16)r;
}
__device__ __forceinline__ float bf_lo(u32 u) { return __uint_as_float(u << 16); }
__device__ __forceinline__ float bf_hi(u32 u) { return __uint_as_float(u & 0xFFFF0000u); }

// ---------------------------------------------------------------------------
// Fused: blocks [0,BASIS_BLOCKS) compute hb bf16 [N][64][4]; the rest histogram
// dst into counts. Independent work, one launch.
// ---------------------------------------------------------------------------
__global__ __launch_bounds__(256) void k_basis_hist(
    const float* __restrict__ x, const float* __restrict__ bases,
    u16* __restrict__ hb,
    const int* __restrict__ dst, u32* __restrict__ counts)
{
    if (blockIdx.x < BASIS_BLOCKS) {
        const int t = threadIdx.x;
        const int o = t >> 2;
        const int b = t & 3;
        float vreg[64];
#pragma unroll
        for (int i = 0; i < 64; ++i)
            vreg[i] = bases[b * 4096 + i * 64 + o];
        for (int n = blockIdx.x; n < N_NODES; n += BASIS_BLOCKS) {
            const float* xr = x + (size_t)n * 64;
            float acc = 0.f;
#pragma unroll
            for (int i = 0; i < 64; ++i)
                acc = fmaf(xr[i], vreg[i], acc);
            hb[(size_t)n * 256 + t] = f2bf(acc);
        }
    } else {
        const int bb = blockIdx.x - BASIS_BLOCKS;
        for (int e = bb * 256 + threadIdx.x; e < N_EDGES; e += HIST_BLOCKS * 256)
            atomicAdd(&counts[dst[e]], 1u);
    }
}

// ---------------------------------------------------------------------------
// Block-level exclusive scan via wave shuffles (2 barriers).
// ---------------------------------------------------------------------------
__global__ __launch_bounds__(1024) void k_scan_block(
    const u32* __restrict__ counts, u32* __restrict__ offs,
    u32* __restrict__ bsums)
{
    __shared__ u32 wsum[16];
    const int t = threadIdx.x;
    const int lane = t & 63, wid = t >> 6;
    const int idx = blockIdx.x * 1024 + t;
    const u32 v = (idx < NBINS) ? counts[idx] : 0u;
    u32 s = v;
#pragma unroll
    for (int off = 1; off < 64; off <<= 1) {
        u32 u = __shfl_up(s, off, 64);
        if (lane >= off) s += u;
    }
    if (lane == 63) wsum[wid] = s;
    __syncthreads();
    if (wid == 0) {
        u32 w = (lane < 16) ? wsum[lane] : 0u;
#pragma unroll
        for (int off = 1; off < 16; off <<= 1) {
            u32 u = __shfl_up(w, off, 64);
            if (lane >= off) w += u;
        }
        if (lane < 16) wsum[lane] = w;  // inclusive wave-sum scan
    }
    __syncthreads();
    const u32 prefix = (wid > 0) ? wsum[wid - 1] : 0u;
    const u32 incl = s + prefix;
    if (idx < NBINS) offs[idx] = incl - v;      // exclusive
    if (t == 1023) bsums[blockIdx.x] = incl;    // block total
}

__global__ __launch_bounds__(128) void k_scan_sums(
    const u32* __restrict__ bsums, u32* __restrict__ boffs, int nb)
{
    __shared__ u32 s[128];
    const int t = threadIdx.x;
    u32 v = (t < nb) ? bsums[t] : 0u;
    s[t] = v;
    __syncthreads();
#pragma unroll
    for (int off = 1; off < 128; off <<= 1) {
        u32 xv = (t >= off) ? s[t - off] : 0u;
        __syncthreads();
        s[t] += xv;
        __syncthreads();
    }
    boffs[t] = s[t] - v;
}

__global__ __launch_bounds__(256) void k_scatter(
    const int* __restrict__ src, const int* __restrict__ dst,
    const int* __restrict__ et,
    const u32* __restrict__ offs, const u32* __restrict__ boffs,
    u32* __restrict__ cursor, u32* __restrict__ packed)
{
    int e = blockIdx.x * 256 + threadIdx.x;
    if (e >= N_EDGES) return;
    const int d = dst[e];
    u32 pos = offs[d] + boffs[d >> 10] + atomicAdd(&cursor[d], 1u);
    packed[pos] = (u32)src[e] | ((u32)et[e] << 20);
}

// ---------------------------------------------------------------------------
// One wave per dst node. Records batch-loaded (one coalesced load per <=64
// edges), extracted via v_readlane (scalar). Gathers unrolled x4 for MLP.
// Self-loop weights staged in LDS. Fused LeakyReLU + LayerNorm epilogue.
// ---------------------------------------------------------------------------
__global__ __launch_bounds__(256) void k_agg_final(
    const u16* __restrict__ hb, const float4* __restrict__ comp,
    const u32* __restrict__ packed,
    const u32* __restrict__ offs, const u32* __restrict__ boffs,
    const u32* __restrict__ counts,
    const float* __restrict__ x, const float* __restrict__ loopw,
    const float* __restrict__ bias, const float* __restrict__ gamma,
    const float* __restrict__ beta, float* __restrict__ out)
{
    __shared__ float wlds[4096];
    const int t = threadIdx.x;
    for (int i = t; i < 4096; i += 256) wlds[i] = loopw[i];
    __syncthreads();

    const int lane = t & 63;
    const int wid = t >> 6;
    const float bs = bias[lane], gm = gamma[lane], bt = beta[lane];
    const int waves = gridDim.x * 4;
    const u16* hbl = hb + lane * 4;  // per-lane 8B slice base

    for (int n0 = blockIdx.x * 4 + wid; n0 < N_NODES; n0 += waves) {
        const int n = __builtin_amdgcn_readfirstlane(n0);
        const u32 base = offs[n] + boffs[n >> 10];
        const u32 deg = counts[n];
        float acc = 0.f;
        u32 done = 0;
        while (done < deg) {
            u32 cnt = deg - done;
            if (cnt > 64u) cnt = 64u;
            const u32 li = ((u32)lane < cnt) ? (u32)lane : 0u;
            const u32 recs = packed[base + done + li];
            u32 k = 0;
            for (; k + 4 <= cnt; k += 4) {
                const u32 r0 = (u32)__builtin_amdgcn_readlane((int)recs, (int)(k + 0));
                const u32 r1 = (u32)__builtin_amdgcn_readlane((int)recs, (int)(k + 1));
                const u32 r2 = (u32)__builtin_amdgcn_readlane((int)recs, (int)(k + 2));
                const u32 r3 = (u32)__builtin_amdgcn_readlane((int)recs, (int)(k + 3));
                const float4 c0 = comp[r0 >> 20];
                const float4 c1 = comp[r1 >> 20];
                const float4 c2 = comp[r2 >> 20];
                const float4 c3 = comp[r3 >> 20];
                const uint2 h0 = *(const uint2*)(hbl + (size_t)(r0 & 0xFFFFFu) * 256);
                const uint2 h1 = *(const uint2*)(hbl + (size_t)(r1 & 0xFFFFFu) * 256);
                const uint2 h2 = *(const uint2*)(hbl + (size_t)(r2 & 0xFFFFFu) * 256);
                const uint2 h3 = *(const uint2*)(hbl + (size_t)(r3 & 0xFFFFFu) * 256);
                acc += c0.x * bf_lo(h0.x) + c0.y * bf_hi(h0.x)
                     + c0.z * bf_lo(h0.y) + c0.w * bf_hi(h0.y);
                acc += c1.x * bf_lo(h1.x) + c1.y * bf_hi(h1.x)
                     + c1.z * bf_lo(h1.y) + c1.w * bf_hi(h1.y);
                acc += c2.x * bf_lo(h2.x) + c2.y * bf_hi(h2.x)
                     + c2.z * bf_lo(h2.y) + c2.w * bf_hi(h2.y);
                acc += c3.x * bf_lo(h3.x) + c3.y * bf_hi(h3.x)
                     + c3.z * bf_lo(h3.y) + c3.w * bf_hi(h3.y);
            }
            for (; k < cnt; ++k) {
                const u32 r0 = (u32)__builtin_amdgcn_readlane((int)recs, (int)k);
                const float4 c0 = comp[r0 >> 20];
                const uint2 h0 = *(const uint2*)(hbl + (size_t)(r0 & 0xFFFFFu) * 256);
                acc += c0.x * bf_lo(h0.x) + c0.y * bf_hi(h0.x)
                     + c0.z * bf_lo(h0.y) + c0.w * bf_hi(h0.y);
            }
            done += cnt;
        }
        // self-loop: x row is wave-uniform (s_loads), weights from LDS
        const float* xr = x + (size_t)n * 64;
        float sl = 0.f;
#pragma unroll
        for (int i = 0; i < 64; ++i)
            sl = fmaf(xr[i], wlds[i * 64 + lane], sl);
        float v = acc + sl + bs;
        v = (v >= 0.f) ? v : 0.1f * v;
        float s1 = v;
#pragma unroll
        for (int m = 32; m >= 1; m >>= 1) s1 += __shfl_xor(s1, m, 64);
        const float mu = s1 * (1.f / 64.f);
        const float dv = v - mu;
        float s2 = dv * dv;
#pragma unroll
        for (int m = 32; m >= 1; m >>= 1) s2 += __shfl_xor(s2, m, 64);
        const float var = s2 * (1.f / 64.f);
        out[(size_t)n * 64 + lane] = dv * rsqrtf(var + LN_EPS) * gm + bt;
    }
}

// ---------------------------------------------------------------------------
// Fallback (tiny ws): direct per-edge compute with atomics + separate finalize.
// ---------------------------------------------------------------------------
__global__ __launch_bounds__(256) void k_edge_direct(
    const float* __restrict__ x, const float* __restrict__ bases,
    const float* __restrict__ comp,
    const int* __restrict__ src, const int* __restrict__ dst,
    const int* __restrict__ et, float* __restrict__ agg)
{
    const int lane = threadIdx.x & 63;
    int e = blockIdx.x * 4 + (threadIdx.x >> 6);
    if (e >= N_EDGES) return;
    e = __builtin_amdgcn_readfirstlane(e);
    const int s = src[e], d = dst[e], r = et[e];
    const float4 c = *(const float4*)(comp + r * 4);
    const float* xr = x + (size_t)s * 64;
    float acc = 0.f;
    for (int i = 0; i < 64; ++i) {
        const float w = c.x * bases[i * 64 + lane]
                      + c.y * bases[4096 + i * 64 + lane]
                      + c.z * bases[8192 + i * 64 + lane]
                      + c.w * bases[12288 + i * 64 + lane];
        acc = fmaf(xr[i], w, acc);
    }
    atomicAdd(&agg[(size_t)d * 64 + lane], acc);
}

__global__ __launch_bounds__(256) void k_finalize(
    const float* __restrict__ x, const float* __restrict__ loopw,
    const float* __restrict__ bias, const float* __restrict__ gamma,
    const float* __restrict__ beta, float* __restrict__ out)
{
    __shared__ float wlds[4096];
    const int t = threadIdx.x;
    for (int i = t; i < 4096; i += 256) wlds[i] = loopw[i];
    __syncthreads();
    const int lane = t & 63;
    const int wid = t >> 6;
    const float bs = bias[lane], gm = gamma[lane], bt = beta[lane];
    const int waves = gridDim.x * 4;
    for (int n = blockIdx.x * 4 + wid; n < N_NODES; n += waves) {
        const float* xr = x + (size_t)n * 64;
        float sl = 0.f;
#pragma unroll
        for (int i = 0; i < 64; ++i)
            sl = fmaf(xr[i], wlds[i * 64 + lane], sl);
        float v = out[(size_t)n * 64 + lane] + sl + bs;
        v = (v >= 0.f) ? v : 0.1f * v;
        float s1 = v;
#pragma unroll
        for (int m = 32; m >= 1; m >>= 1) s1 += __shfl_xor(s1, m, 64);
        const float mu = s1 * (1.f / 64.f);
        const float dv = v - mu;
        float s2 = dv * dv;
#pragma unroll
        for (int m = 32; m >= 1; m >>= 1) s2 += __shfl_xor(s2, m, 64);
        const float var = s2 * (1.f / 64.f);
        out[(size_t)n * 64 + lane] = dv * rsqrtf(var + LN_EPS) * gm + bt;
    }
}

// ---------------------------------------------------------------------------
extern "C" void kernel_launch(void* const* d_in, const int* in_sizes, int n_in,
                              void* d_out, int out_size, void* d_ws, size_t ws_size,
                              hipStream_t stream) {
    const float* x     = (const float*)d_in[0];
    const float* bases = (const float*)d_in[1];
    const float* comp  = (const float*)d_in[2];
    const float* loopw = (const float*)d_in[3];
    const float* bias  = (const float*)d_in[4];
    const float* gamma = (const float*)d_in[5];
    const float* beta  = (const float*)d_in[6];
    const int*   src   = (const int*)d_in[7];
    const int*   dst   = (const int*)d_in[8];
    const int*   et    = (const int*)d_in[9];
    float* out = (float*)d_out;

    size_t p = 0;
    auto alloc = [&](size_t bytes) {
        size_t cur = p;
        p = (p + bytes + 255) & ~(size_t)255;
        return cur;
    };
    char* ws = (char*)d_ws;
    const size_t o_counts = alloc((size_t)NBINS * sizeof(u32));
    const size_t o_cursor = alloc((size_t)NBINS * sizeof(u32));
    const size_t zero_len = p - o_counts;  // counts+cursor in one memset
    const size_t o_hb     = alloc((size_t)N_NODES * 256 * sizeof(u16)); // 51.2 MB
    const size_t o_offs   = alloc((size_t)NBINS * sizeof(u32));
    const size_t o_bsums  = alloc(128 * sizeof(u32));
    const size_t o_boffs  = alloc(128 * sizeof(u32));
    const size_t o_packed = alloc((size_t)N_EDGES * sizeof(u32));       // 6.4 MB
    const size_t need = p;

    const int edge_blocks = (N_EDGES + 255) / 256;

    if (ws_size >= need) {
        u32* counts = (u32*)(ws + o_counts);
        u32* cursor = (u32*)(ws + o_cursor);
        u16* hb     = (u16*)(ws + o_hb);
        u32* offs   = (u32*)(ws + o_offs);
        u32* bsums  = (u32*)(ws + o_bsums);
        u32* boffs  = (u32*)(ws + o_boffs);
        u32* packed = (u32*)(ws + o_packed);

        hipMemsetAsync(ws + o_counts, 0, zero_len, stream);
        k_basis_hist<<<BASIS_BLOCKS + HIST_BLOCKS, 256, 0, stream>>>(
            x, bases, hb, dst, counts);
        const int scan_blocks = (NBINS + 1023) / 1024;  // 98
        k_scan_block<<<scan_blocks, 1024, 0, stream>>>(counts, offs, bsums);
        k_scan_sums<<<1, 128, 0, stream>>>(bsums, boffs, scan_blocks);
        k_scatter<<<edge_blocks, 256, 0, stream>>>(src, dst, et, offs, boffs,
                                                   cursor, packed);
        k_agg_final<<<2048, 256, 0, stream>>>(hb, (const float4*)comp, packed,
                                              offs, boffs, counts, x, loopw,
                                              bias, gamma, beta, out);
    } else {
        hipMemsetAsync(d_out, 0, (size_t)N_NODES * 64 * sizeof(float), stream);
        k_edge_direct<<<(N_EDGES + 3) / 4, 256, 0, stream>>>(
            x, bases, comp, src, dst, et, out);
        k_finalize<<<2048, 256, 0, stream>>>(x, loopw, bias, gamma, beta, out);
    }
}

// Round 4
// 357.805 us; speedup vs baseline: 1.4918x; 1.1241x over previous
//
#include <hip/hip_runtime.h>

#define N_NODES 100000
#define N_EDGES 1600000
#define NBINS   100000
#define LN_EPS  1e-5f

#define BASIS_BLOCKS 2048
#define SL_BLOCKS    512
#define HIST_BLOCKS  1024

typedef unsigned int u32;
typedef unsigned short u16;

__device__ __forceinline__ u16 f2bf(float f) {
    u32 u = __float_as_uint(f);
    u32 r = (u + 0x7FFFu + ((u >> 16) & 1u)) >> 16;   // round-to-nearest-even
    return (u16)r;
}
__device__ __forceinline__ float bf_lo(u32 u) { return __uint_as_float(u << 16); }
__device__ __forceinline__ float bf_hi(u32 u) { return __uint_as_float(u & 0xFFFF0000u); }

// ---------------------------------------------------------------------------
// Fused independent work, one launch:
//   blocks [0, BASIS):            hb[n][o][b] bf16-pair via lane-broadcast
//   blocks [BASIS, BASIS+SL):     sl[n][o] = bias[o] + x[n]·loopw[:,o]
//   blocks [BASIS+SL, +HIST):     histogram of dst
// x-row delivery: ONE coalesced load per wave (lane i holds x[n][i]), then
// v_readlane broadcasts element i into an SGPR for v_fmac. No per-element
// memory traffic, 2-deep node prefetch.
// ---------------------------------------------------------------------------
__global__ __launch_bounds__(256) void k_basis_sl_hist(
    const float* __restrict__ x, const float* __restrict__ bases,
    const float* __restrict__ loopw, const float* __restrict__ bias,
    u32* __restrict__ hb32,           // [N,128] u32 (= [N,256] u16, b innermost)
    float* __restrict__ sl,           // [N,64]
    const int* __restrict__ dst, u32* __restrict__ counts)
{
    const int t = threadIdx.x;
    const int lane = t & 63;

    if (blockIdx.x < BASIS_BLOCKS) {
        // thread: sub = t&127 -> o = sub>>1, bp = sub&1 (b = 2bp, 2bp+1)
        // half = t>>7 -> node parity within the block's pair
        const int sub = t & 127;
        const int half = t >> 7;
        const int o = sub >> 1, bp = sub & 1;
        float wx[64], wy[64];
#pragma unroll
        for (int i = 0; i < 64; ++i) {
            wx[i] = bases[(2 * bp) * 4096 + i * 64 + o];
            wy[i] = bases[(2 * bp + 1) * 4096 + i * 64 + o];
        }
        const int stride = BASIS_BLOCKS * 2;
        int n = blockIdx.x * 2 + half;
        float xv = (n < N_NODES) ? x[(size_t)n * 64 + lane] : 0.f;
        while (n < N_NODES) {
            const int n2 = n + stride;
            float xv2 = 0.f;
            if (n2 < N_NODES) xv2 = x[(size_t)n2 * 64 + lane];
            const int xb = __float_as_int(xv);
            float ax = 0.f, ay = 0.f;
#pragma unroll
            for (int i = 0; i < 64; ++i) {
                const float s = __int_as_float(__builtin_amdgcn_readlane(xb, i));
                ax = fmaf(s, wx[i], ax);
                ay = fmaf(s, wy[i], ay);
            }
            hb32[(size_t)n * 128 + sub] = ((u32)f2bf(ay) << 16) | f2bf(ax);
            n = n2; xv = xv2;
        }
    } else if (blockIdx.x < BASIS_BLOCKS + SL_BLOCKS) {
        // one wave per node: lane = o
        const int bb = blockIdx.x - BASIS_BLOCKS;
        const int sub = t >> 6;
        float wreg[64];
#pragma unroll
        for (int i = 0; i < 64; ++i)
            wreg[i] = loopw[i * 64 + lane];
        const float bs = bias[lane];
        const int stride = SL_BLOCKS * 4;
        int n = bb * 4 + sub;
        float xv = (n < N_NODES) ? x[(size_t)n * 64 + lane] : 0.f;
        while (n < N_NODES) {
            const int n2 = n + stride;
            float xv2 = 0.f;
            if (n2 < N_NODES) xv2 = x[(size_t)n2 * 64 + lane];
            const int xb = __float_as_int(xv);
            float acc = bs;
#pragma unroll
            for (int i = 0; i < 64; ++i) {
                const float s = __int_as_float(__builtin_amdgcn_readlane(xb, i));
                acc = fmaf(s, wreg[i], acc);
            }
            sl[(size_t)n * 64 + lane] = acc;
            n = n2; xv = xv2;
        }
    } else {
        const int bb = blockIdx.x - BASIS_BLOCKS - SL_BLOCKS;
        for (int e = bb * 256 + t; e < N_EDGES; e += HIST_BLOCKS * 256)
            atomicAdd(&counts[dst[e]], 1u);
    }
}

// ---------------------------------------------------------------------------
// Block-level exclusive scan via wave shuffles (2 barriers).
// ---------------------------------------------------------------------------
__global__ __launch_bounds__(1024) void k_scan_block(
    const u32* __restrict__ counts, u32* __restrict__ offs,
    u32* __restrict__ bsums)
{
    __shared__ u32 wsum[16];
    const int t = threadIdx.x;
    const int lane = t & 63, wid = t >> 6;
    const int idx = blockIdx.x * 1024 + t;
    const u32 v = (idx < NBINS) ? counts[idx] : 0u;
    u32 s = v;
#pragma unroll
    for (int off = 1; off < 64; off <<= 1) {
        u32 u = __shfl_up(s, off, 64);
        if (lane >= off) s += u;
    }
    if (lane == 63) wsum[wid] = s;
    __syncthreads();
    if (wid == 0) {
        u32 w = (lane < 16) ? wsum[lane] : 0u;
#pragma unroll
        for (int off = 1; off < 16; off <<= 1) {
            u32 u = __shfl_up(w, off, 64);
            if (lane >= off) w += u;
        }
        if (lane < 16) wsum[lane] = w;
    }
    __syncthreads();
    const u32 prefix = (wid > 0) ? wsum[wid - 1] : 0u;
    const u32 incl = s + prefix;
    if (idx < NBINS) offs[idx] = incl - v;
    if (t == 1023) bsums[blockIdx.x] = incl;
}

__global__ __launch_bounds__(128) void k_scan_sums(
    const u32* __restrict__ bsums, u32* __restrict__ boffs, int nb)
{
    __shared__ u32 s[128];
    const int t = threadIdx.x;
    u32 v = (t < nb) ? bsums[t] : 0u;
    s[t] = v;
    __syncthreads();
#pragma unroll
    for (int off = 1; off < 128; off <<= 1) {
        u32 xv = (t >= off) ? s[t - off] : 0u;
        __syncthreads();
        s[t] += xv;
        __syncthreads();
    }
    boffs[t] = s[t] - v;
}

__global__ __launch_bounds__(256) void k_scatter(
    const int* __restrict__ src, const int* __restrict__ dst,
    const int* __restrict__ et,
    const u32* __restrict__ offs, const u32* __restrict__ boffs,
    u32* __restrict__ cursor, u32* __restrict__ packed)
{
    int e = blockIdx.x * 256 + threadIdx.x;
    if (e >= N_EDGES) return;
    const int d = dst[e];
    u32 pos = offs[d] + boffs[d >> 10] + atomicAdd(&cursor[d], 1u);
    packed[pos] = (u32)src[e] | ((u32)et[e] << 20);
}

// ---------------------------------------------------------------------------
// One wave per dst node. Records batch-loaded coalesced, extracted with
// v_readlane; gathers unrolled x4. Epilogue: load precomputed self-loop,
// LeakyReLU + wave-wide LayerNorm. No LDS anywhere.
// ---------------------------------------------------------------------------
__global__ __launch_bounds__(256) void k_agg_final(
    const u16* __restrict__ hb, const float4* __restrict__ comp,
    const u32* __restrict__ packed,
    const u32* __restrict__ offs, const u32* __restrict__ boffs,
    const u32* __restrict__ counts,
    const float* __restrict__ sl,
    const float* __restrict__ gamma, const float* __restrict__ beta,
    float* __restrict__ out)
{
    const int t = threadIdx.x;
    const int lane = t & 63;
    const int wid = t >> 6;
    const float gm = gamma[lane], bt = beta[lane];
    const int waves = gridDim.x * 4;
    const u16* hbl = hb + lane * 4;

    for (int n0 = blockIdx.x * 4 + wid; n0 < N_NODES; n0 += waves) {
        const int n = __builtin_amdgcn_readfirstlane(n0);
        const u32 base = offs[n] + boffs[n >> 10];
        const u32 deg = counts[n];
        float acc = 0.f;
        u32 done = 0;
        while (done < deg) {
            u32 cnt = deg - done;
            if (cnt > 64u) cnt = 64u;
            const u32 li = ((u32)lane < cnt) ? (u32)lane : 0u;
            const u32 recs = packed[base + done + li];
            u32 k = 0;
            for (; k + 4 <= cnt; k += 4) {
                const u32 r0 = (u32)__builtin_amdgcn_readlane((int)recs, (int)(k + 0));
                const u32 r1 = (u32)__builtin_amdgcn_readlane((int)recs, (int)(k + 1));
                const u32 r2 = (u32)__builtin_amdgcn_readlane((int)recs, (int)(k + 2));
                const u32 r3 = (u32)__builtin_amdgcn_readlane((int)recs, (int)(k + 3));
                const float4 c0 = comp[r0 >> 20];
                const float4 c1 = comp[r1 >> 20];
                const float4 c2 = comp[r2 >> 20];
                const float4 c3 = comp[r3 >> 20];
                const uint2 h0 = *(const uint2*)(hbl + (size_t)(r0 & 0xFFFFFu) * 256);
                const uint2 h1 = *(const uint2*)(hbl + (size_t)(r1 & 0xFFFFFu) * 256);
                const uint2 h2 = *(const uint2*)(hbl + (size_t)(r2 & 0xFFFFFu) * 256);
                const uint2 h3 = *(const uint2*)(hbl + (size_t)(r3 & 0xFFFFFu) * 256);
                acc += c0.x * bf_lo(h0.x) + c0.y * bf_hi(h0.x)
                     + c0.z * bf_lo(h0.y) + c0.w * bf_hi(h0.y);
                acc += c1.x * bf_lo(h1.x) + c1.y * bf_hi(h1.x)
                     + c1.z * bf_lo(h1.y) + c1.w * bf_hi(h1.y);
                acc += c2.x * bf_lo(h2.x) + c2.y * bf_hi(h2.x)
                     + c2.z * bf_lo(h2.y) + c2.w * bf_hi(h2.y);
                acc += c3.x * bf_lo(h3.x) + c3.y * bf_hi(h3.x)
                     + c3.z * bf_lo(h3.y) + c3.w * bf_hi(h3.y);
            }
            for (; k < cnt; ++k) {
                const u32 r0 = (u32)__builtin_amdgcn_readlane((int)recs, (int)k);
                const float4 c0 = comp[r0 >> 20];
                const uint2 h0 = *(const uint2*)(hbl + (size_t)(r0 & 0xFFFFFu) * 256);
                acc += c0.x * bf_lo(h0.x) + c0.y * bf_hi(h0.x)
                     + c0.z * bf_lo(h0.y) + c0.w * bf_hi(h0.y);
            }
            done += cnt;
        }
        float v = acc + sl[(size_t)n * 64 + lane];
        v = (v >= 0.f) ? v : 0.1f * v;
        float s1 = v;
#pragma unroll
        for (int m = 32; m >= 1; m >>= 1) s1 += __shfl_xor(s1, m, 64);
        const float mu = s1 * (1.f / 64.f);
        const float dv = v - mu;
        float s2 = dv * dv;
#pragma unroll
        for (int m = 32; m >= 1; m >>= 1) s2 += __shfl_xor(s2, m, 64);
        const float var = s2 * (1.f / 64.f);
        out[(size_t)n * 64 + lane] = dv * rsqrtf(var + LN_EPS) * gm + bt;
    }
}

// ---------------------------------------------------------------------------
// Fallback (tiny ws): direct per-edge compute with atomics + separate finalize.
// ---------------------------------------------------------------------------
__global__ __launch_bounds__(256) void k_edge_direct(
    const float* __restrict__ x, const float* __restrict__ bases,
    const float* __restrict__ comp,
    const int* __restrict__ src, const int* __restrict__ dst,
    const int* __restrict__ et, float* __restrict__ agg)
{
    const int lane = threadIdx.x & 63;
    int e = blockIdx.x * 4 + (threadIdx.x >> 6);
    if (e >= N_EDGES) return;
    e = __builtin_amdgcn_readfirstlane(e);
    const int s = src[e], d = dst[e], r = et[e];
    const float4 c = *(const float4*)(comp + r * 4);
    const float* xr = x + (size_t)s * 64;
    float acc = 0.f;
    for (int i = 0; i < 64; ++i) {
        const float w = c.x * bases[i * 64 + lane]
                      + c.y * bases[4096 + i * 64 + lane]
                      + c.z * bases[8192 + i * 64 + lane]
                      + c.w * bases[12288 + i * 64 + lane];
        acc = fmaf(xr[i], w, acc);
    }
    atomicAdd(&agg[(size_t)d * 64 + lane], acc);
}

__global__ __launch_bounds__(256) void k_finalize(
    const float* __restrict__ x, const float* __restrict__ loopw,
    const float* __restrict__ bias, const float* __restrict__ gamma,
    const float* __restrict__ beta, float* __restrict__ out)
{
    const int t = threadIdx.x;
    const int lane = t & 63;
    const int wid = t >> 6;
    float wreg[64];
#pragma unroll
    for (int i = 0; i < 64; ++i)
        wreg[i] = loopw[i * 64 + lane];
    const float bs = bias[lane], gm = gamma[lane], bt = beta[lane];
    const int waves = gridDim.x * 4;
    for (int n = blockIdx.x * 4 + wid; n < N_NODES; n += waves) {
        float xv = x[(size_t)n * 64 + lane];
        const int xb = __float_as_int(xv);
        float slv = bs;
#pragma unroll
        for (int i = 0; i < 64; ++i) {
            const float s = __int_as_float(__builtin_amdgcn_readlane(xb, i));
            slv = fmaf(s, wreg[i], slv);
        }
        float v = out[(size_t)n * 64 + lane] + slv;
        v = (v >= 0.f) ? v : 0.1f * v;
        float s1 = v;
#pragma unroll
        for (int m = 32; m >= 1; m >>= 1) s1 += __shfl_xor(s1, m, 64);
        const float mu = s1 * (1.f / 64.f);
        const float dv = v - mu;
        float s2 = dv * dv;
#pragma unroll
        for (int m = 32; m >= 1; m >>= 1) s2 += __shfl_xor(s2, m, 64);
        const float var = s2 * (1.f / 64.f);
        out[(size_t)n * 64 + lane] = dv * rsqrtf(var + LN_EPS) * gm + bt;
    }
}

// ---------------------------------------------------------------------------
extern "C" void kernel_launch(void* const* d_in, const int* in_sizes, int n_in,
                              void* d_out, int out_size, void* d_ws, size_t ws_size,
                              hipStream_t stream) {
    const float* x     = (const float*)d_in[0];
    const float* bases = (const float*)d_in[1];
    const float* comp  = (const float*)d_in[2];
    const float* loopw = (const float*)d_in[3];
    const float* bias  = (const float*)d_in[4];
    const float* gamma = (const float*)d_in[5];
    const float* beta  = (const float*)d_in[6];
    const int*   src   = (const int*)d_in[7];
    const int*   dst   = (const int*)d_in[8];
    const int*   et    = (const int*)d_in[9];
    float* out = (float*)d_out;

    size_t p = 0;
    auto alloc = [&](size_t bytes) {
        size_t cur = p;
        p = (p + bytes + 255) & ~(size_t)255;
        return cur;
    };
    char* ws = (char*)d_ws;
    const size_t o_counts = alloc((size_t)NBINS * sizeof(u32));
    const size_t o_cursor = alloc((size_t)NBINS * sizeof(u32));
    const size_t zero_len = p - o_counts;
    const size_t o_hb     = alloc((size_t)N_NODES * 256 * sizeof(u16)); // 51.2 MB
    const size_t o_sl     = alloc((size_t)N_NODES * 64 * sizeof(float)); // 25.6 MB
    const size_t o_offs   = alloc((size_t)NBINS * sizeof(u32));
    const size_t o_bsums  = alloc(128 * sizeof(u32));
    const size_t o_boffs  = alloc(128 * sizeof(u32));
    const size_t o_packed = alloc((size_t)N_EDGES * sizeof(u32));       // 6.4 MB
    const size_t need = p;

    const int edge_blocks = (N_EDGES + 255) / 256;

    if (ws_size >= need) {
        u32* counts = (u32*)(ws + o_counts);
        u32* cursor = (u32*)(ws + o_cursor);
        u16* hb     = (u16*)(ws + o_hb);
        float* sl   = (float*)(ws + o_sl);
        u32* offs   = (u32*)(ws + o_offs);
        u32* bsums  = (u32*)(ws + o_bsums);
        u32* boffs  = (u32*)(ws + o_boffs);
        u32* packed = (u32*)(ws + o_packed);

        hipMemsetAsync(ws + o_counts, 0, zero_len, stream);
        k_basis_sl_hist<<<BASIS_BLOCKS + SL_BLOCKS + HIST_BLOCKS, 256, 0, stream>>>(
            x, bases, loopw, bias, (u32*)hb, sl, dst, counts);
        const int scan_blocks = (NBINS + 1023) / 1024;  // 98
        k_scan_block<<<scan_blocks, 1024, 0, stream>>>(counts, offs, bsums);
        k_scan_sums<<<1, 128, 0, stream>>>(bsums, boffs, scan_blocks);
        k_scatter<<<edge_blocks, 256, 0, stream>>>(src, dst, et, offs, boffs,
                                                   cursor, packed);
        k_agg_final<<<2048, 256, 0, stream>>>(hb, (const float4*)comp, packed,
                                              offs, boffs, counts, sl,
                                              gamma, beta, out);
    } else {
        hipMemsetAsync(d_out, 0, (size_t)N_NODES * 64 * sizeof(float), stream);
        k_edge_direct<<<(N_EDGES + 3) / 4, 256, 0, stream>>>(
            x, bases, comp, src, dst, et, out);
        k_finalize<<<2048, 256, 0, stream>>>(x, loopw, bias, gamma, beta, out);
    }
}

// Round 5
// 303.097 us; speedup vs baseline: 1.7611x; 1.1805x over previous
//
#include <hip/hip_runtime.h>

#define N_NODES 100000
#define N_EDGES 1600000
#define NBINS   100000
#define LN_EPS  1e-5f

#define HIST_BLOCKS  1024

typedef unsigned int u32;
typedef unsigned short u16;
typedef __attribute__((ext_vector_type(8))) short short8;
typedef __attribute__((ext_vector_type(4))) float f32x4;

__device__ __forceinline__ u16 f2bf(float f) {
    u32 u = __float_as_uint(f);
    u32 r = (u + 0x7FFFu + ((u >> 16) & 1u)) >> 16;   // round-to-nearest-even
    return (u16)r;
}
__device__ __forceinline__ float bf_lo(u32 u) { return __uint_as_float(u << 16); }
__device__ __forceinline__ float bf_hi(u32 u) { return __uint_as_float(u & 0xFFFF0000u); }

// ---------------------------------------------------------------------------
// Fused: block 0 builds the fragmented bf16 weight table Wf for the GEMM;
// blocks [1, 1+HIST) histogram dst. One launch, independent work.
// Wf[ct][ks][lane][j] = W[k][c], k = ks*32 + (lane>>4)*8 + j, c = ct*16+(lane&15)
//   c < 256 : W[k][c] = bases[c&3][k][c>>2]   (so GEMM col c == hb col o*4+b)
//   c >= 256: W[k][c] = loopw[k][c-256]
// ---------------------------------------------------------------------------
__global__ __launch_bounds__(256) void k_prep_hist(
    const float* __restrict__ bases, const float* __restrict__ loopw,
    u16* __restrict__ wf,
    const int* __restrict__ dst, u32* __restrict__ counts)
{
    const int t = threadIdx.x;
    if (blockIdx.x == 0) {
        for (int idx = t; idx < 20 * 2 * 64 * 8; idx += 256) {
            const int j = idx & 7;
            const int l = (idx >> 3) & 63;
            const int ks = (idx >> 9) & 1;
            const int ct = idx >> 10;
            const int k = ks * 32 + (l >> 4) * 8 + j;
            const int c = ct * 16 + (l & 15);
            float v;
            if (c < 256) v = bases[(c & 3) * 4096 + k * 64 + (c >> 2)];
            else         v = loopw[k * 64 + (c - 256)];
            wf[idx] = f2bf(v);
        }
    } else {
        const int bb = blockIdx.x - 1;
        for (int e = bb * 256 + t; e < N_EDGES; e += HIST_BLOCKS * 256)
            atomicAdd(&counts[dst[e]], 1u);
    }
}

// ---------------------------------------------------------------------------
// MFMA GEMM: [N,64]f32 (cast to bf16 in-reg) @ Wf[64,320]bf16.
// One wave per 16-row tile, all 320 cols: 40x mfma_f32_16x16x32_bf16.
// cols 0..255 -> hb bf16 [N][256]; cols 256..319 -> sl f32 [N][64] (+bias).
// C/D layout (HW-verified): col = lane&15, row = (lane>>4)*4 + reg.
// ---------------------------------------------------------------------------
__global__ __launch_bounds__(256) void k_gemm(
    const float* __restrict__ x, const short8* __restrict__ wf,
    const float* __restrict__ bias,
    u16* __restrict__ hb, float* __restrict__ sl)
{
    const int lane = threadIdx.x & 63;
    const int wid = threadIdx.x >> 6;
    const int m = lane & 15, kg = lane >> 4;
    const int ntiles = N_NODES / 16;              // 6250 exact
    for (int tile = blockIdx.x * 4 + wid; tile < ntiles; tile += gridDim.x * 4) {
        const int base = tile * 16;
        const float* xr = x + (size_t)(base + m) * 64 + kg * 8;
        const float4 p0 = *(const float4*)(xr);
        const float4 p1 = *(const float4*)(xr + 4);
        const float4 q0 = *(const float4*)(xr + 32);
        const float4 q1 = *(const float4*)(xr + 36);
        union { u32 w[4]; short8 v; } ua, ub;
        ua.w[0] = (u32)f2bf(p0.x) | ((u32)f2bf(p0.y) << 16);
        ua.w[1] = (u32)f2bf(p0.z) | ((u32)f2bf(p0.w) << 16);
        ua.w[2] = (u32)f2bf(p1.x) | ((u32)f2bf(p1.y) << 16);
        ua.w[3] = (u32)f2bf(p1.z) | ((u32)f2bf(p1.w) << 16);
        ub.w[0] = (u32)f2bf(q0.x) | ((u32)f2bf(q0.y) << 16);
        ub.w[1] = (u32)f2bf(q0.z) | ((u32)f2bf(q0.w) << 16);
        ub.w[2] = (u32)f2bf(q1.x) | ((u32)f2bf(q1.y) << 16);
        ub.w[3] = (u32)f2bf(q1.z) | ((u32)f2bf(q1.w) << 16);
        const short8 a0 = ua.v, a1 = ub.v;
#pragma unroll
        for (int ct = 0; ct < 20; ++ct) {
            const short8 b0 = wf[(ct * 2 + 0) * 64 + lane];
            const short8 b1 = wf[(ct * 2 + 1) * 64 + lane];
            f32x4 acc = {0.f, 0.f, 0.f, 0.f};
            acc = __builtin_amdgcn_mfma_f32_16x16x32_bf16(a0, b0, acc, 0, 0, 0);
            acc = __builtin_amdgcn_mfma_f32_16x16x32_bf16(a1, b1, acc, 0, 0, 0);
            if (ct < 16) {
#pragma unroll
                for (int r = 0; r < 4; ++r) {
                    const int ro = base + kg * 4 + r;
                    hb[(size_t)ro * 256 + ct * 16 + m] = f2bf(acc[r]);
                }
            } else {
                const int o = (ct - 16) * 16 + m;
                const float bs = bias[o];
#pragma unroll
                for (int r = 0; r < 4; ++r) {
                    const int ro = base + kg * 4 + r;
                    sl[(size_t)ro * 64 + o] = acc[r] + bs;
                }
            }
        }
    }
}

// ---------------------------------------------------------------------------
// Block-level exclusive scan via wave shuffles.
// ---------------------------------------------------------------------------
__global__ __launch_bounds__(1024) void k_scan_block(
    const u32* __restrict__ counts, u32* __restrict__ offs,
    u32* __restrict__ bsums)
{
    __shared__ u32 wsum[16];
    const int t = threadIdx.x;
    const int lane = t & 63, wid = t >> 6;
    const int idx = blockIdx.x * 1024 + t;
    const u32 v = (idx < NBINS) ? counts[idx] : 0u;
    u32 s = v;
#pragma unroll
    for (int off = 1; off < 64; off <<= 1) {
        u32 u = __shfl_up(s, off, 64);
        if (lane >= off) s += u;
    }
    if (lane == 63) wsum[wid] = s;
    __syncthreads();
    if (wid == 0) {
        u32 w = (lane < 16) ? wsum[lane] : 0u;
#pragma unroll
        for (int off = 1; off < 16; off <<= 1) {
            u32 u = __shfl_up(w, off, 64);
            if (lane >= off) w += u;
        }
        if (lane < 16) wsum[lane] = w;
    }
    __syncthreads();
    const u32 prefix = (wid > 0) ? wsum[wid - 1] : 0u;
    const u32 incl = s + prefix;
    if (idx < NBINS) offs[idx] = incl - v;
    if (t == 1023) bsums[blockIdx.x] = incl;
}

__global__ __launch_bounds__(128) void k_scan_sums(
    const u32* __restrict__ bsums, u32* __restrict__ boffs, int nb)
{
    __shared__ u32 s[128];
    const int t = threadIdx.x;
    u32 v = (t < nb) ? bsums[t] : 0u;
    s[t] = v;
    __syncthreads();
#pragma unroll
    for (int off = 1; off < 128; off <<= 1) {
        u32 xv = (t >= off) ? s[t - off] : 0u;
        __syncthreads();
        s[t] += xv;
        __syncthreads();
    }
    boffs[t] = s[t] - v;
}

__global__ __launch_bounds__(256) void k_scatter(
    const int* __restrict__ src, const int* __restrict__ dst,
    const int* __restrict__ et,
    const u32* __restrict__ offs, const u32* __restrict__ boffs,
    u32* __restrict__ cursor, u32* __restrict__ packed)
{
    int e = blockIdx.x * 256 + threadIdx.x;
    if (e >= N_EDGES) return;
    const int d = dst[e];
    u32 pos = offs[d] + boffs[d >> 10] + atomicAdd(&cursor[d], 1u);
    packed[pos] = (u32)src[e] | ((u32)et[e] << 20);
}

// ---------------------------------------------------------------------------
// One wave per dst node; records batch-loaded coalesced, extracted with
// v_readlane; gathers unrolled x8 for memory-level parallelism.
// ---------------------------------------------------------------------------
__global__ __launch_bounds__(256) void k_agg_final(
    const u16* __restrict__ hb, const float4* __restrict__ comp,
    const u32* __restrict__ packed,
    const u32* __restrict__ offs, const u32* __restrict__ boffs,
    const u32* __restrict__ counts,
    const float* __restrict__ sl,
    const float* __restrict__ gamma, const float* __restrict__ beta,
    float* __restrict__ out)
{
    const int t = threadIdx.x;
    const int lane = t & 63;
    const int wid = t >> 6;
    const float gm = gamma[lane], bt = beta[lane];
    const int waves = gridDim.x * 4;
    const u16* hbl = hb + lane * 4;

    for (int n0 = blockIdx.x * 4 + wid; n0 < N_NODES; n0 += waves) {
        const int n = __builtin_amdgcn_readfirstlane(n0);
        const u32 base = offs[n] + boffs[n >> 10];
        const u32 deg = counts[n];
        float acc = 0.f;
        u32 done = 0;
        while (done < deg) {
            u32 cnt = deg - done;
            if (cnt > 64u) cnt = 64u;
            const u32 li = ((u32)lane < cnt) ? (u32)lane : 0u;
            const u32 recs = packed[base + done + li];
            u32 k = 0;
            for (; k + 8 <= cnt; k += 8) {
                u32 rr[8];
#pragma unroll
                for (int q = 0; q < 8; ++q)
                    rr[q] = (u32)__builtin_amdgcn_readlane((int)recs, (int)(k + q));
                uint2 hh[8];
#pragma unroll
                for (int q = 0; q < 8; ++q)
                    hh[q] = *(const uint2*)(hbl + (size_t)(rr[q] & 0xFFFFFu) * 256);
                float4 cc[8];
#pragma unroll
                for (int q = 0; q < 8; ++q) cc[q] = comp[rr[q] >> 20];
#pragma unroll
                for (int q = 0; q < 8; ++q)
                    acc += cc[q].x * bf_lo(hh[q].x) + cc[q].y * bf_hi(hh[q].x)
                         + cc[q].z * bf_lo(hh[q].y) + cc[q].w * bf_hi(hh[q].y);
            }
            for (; k + 4 <= cnt; k += 4) {
                u32 rr[4];
#pragma unroll
                for (int q = 0; q < 4; ++q)
                    rr[q] = (u32)__builtin_amdgcn_readlane((int)recs, (int)(k + q));
                uint2 hh[4];
#pragma unroll
                for (int q = 0; q < 4; ++q)
                    hh[q] = *(const uint2*)(hbl + (size_t)(rr[q] & 0xFFFFFu) * 256);
                float4 cc[4];
#pragma unroll
                for (int q = 0; q < 4; ++q) cc[q] = comp[rr[q] >> 20];
#pragma unroll
                for (int q = 0; q < 4; ++q)
                    acc += cc[q].x * bf_lo(hh[q].x) + cc[q].y * bf_hi(hh[q].x)
                         + cc[q].z * bf_lo(hh[q].y) + cc[q].w * bf_hi(hh[q].y);
            }
            for (; k < cnt; ++k) {
                const u32 r0 = (u32)__builtin_amdgcn_readlane((int)recs, (int)k);
                const float4 c0 = comp[r0 >> 20];
                const uint2 h0 = *(const uint2*)(hbl + (size_t)(r0 & 0xFFFFFu) * 256);
                acc += c0.x * bf_lo(h0.x) + c0.y * bf_hi(h0.x)
                     + c0.z * bf_lo(h0.y) + c0.w * bf_hi(h0.y);
            }
            done += cnt;
        }
        float v = acc + sl[(size_t)n * 64 + lane];
        v = (v >= 0.f) ? v : 0.1f * v;
        float s1 = v;
#pragma unroll
        for (int mm = 32; mm >= 1; mm >>= 1) s1 += __shfl_xor(s1, mm, 64);
        const float mu = s1 * (1.f / 64.f);
        const float dv = v - mu;
        float s2 = dv * dv;
#pragma unroll
        for (int mm = 32; mm >= 1; mm >>= 1) s2 += __shfl_xor(s2, mm, 64);
        const float var = s2 * (1.f / 64.f);
        out[(size_t)n * 64 + lane] = dv * rsqrtf(var + LN_EPS) * gm + bt;
    }
}

// ---------------------------------------------------------------------------
// Fallback (tiny ws): direct per-edge compute with atomics + separate finalize.
// ---------------------------------------------------------------------------
__global__ __launch_bounds__(256) void k_edge_direct(
    const float* __restrict__ x, const float* __restrict__ bases,
    const float* __restrict__ comp,
    const int* __restrict__ src, const int* __restrict__ dst,
    const int* __restrict__ et, float* __restrict__ agg)
{
    const int lane = threadIdx.x & 63;
    int e = blockIdx.x * 4 + (threadIdx.x >> 6);
    if (e >= N_EDGES) return;
    e = __builtin_amdgcn_readfirstlane(e);
    const int s = src[e], d = dst[e], r = et[e];
    const float4 c = *(const float4*)(comp + r * 4);
    const float* xr = x + (size_t)s * 64;
    float acc = 0.f;
    for (int i = 0; i < 64; ++i) {
        const float w = c.x * bases[i * 64 + lane]
                      + c.y * bases[4096 + i * 64 + lane]
                      + c.z * bases[8192 + i * 64 + lane]
                      + c.w * bases[12288 + i * 64 + lane];
        acc = fmaf(xr[i], w, acc);
    }
    atomicAdd(&agg[(size_t)d * 64 + lane], acc);
}

__global__ __launch_bounds__(256) void k_finalize(
    const float* __restrict__ x, const float* __restrict__ loopw,
    const float* __restrict__ bias, const float* __restrict__ gamma,
    const float* __restrict__ beta, float* __restrict__ out)
{
    const int t = threadIdx.x;
    const int lane = t & 63;
    const int wid = t >> 6;
    float wreg[64];
#pragma unroll
    for (int i = 0; i < 64; ++i)
        wreg[i] = loopw[i * 64 + lane];
    const float bs = bias[lane], gm = gamma[lane], bt = beta[lane];
    const int waves = gridDim.x * 4;
    for (int n = blockIdx.x * 4 + wid; n < N_NODES; n += waves) {
        float xv = x[(size_t)n * 64 + lane];
        const int xb = __float_as_int(xv);
        float slv = bs;
#pragma unroll
        for (int i = 0; i < 64; ++i) {
            const float s = __int_as_float(__builtin_amdgcn_readlane(xb, i));
            slv = fmaf(s, wreg[i], slv);
        }
        float v = out[(size_t)n * 64 + lane] + slv;
        v = (v >= 0.f) ? v : 0.1f * v;
        float s1 = v;
#pragma unroll
        for (int mm = 32; mm >= 1; mm >>= 1) s1 += __shfl_xor(s1, mm, 64);
        const float mu = s1 * (1.f / 64.f);
        const float dv = v - mu;
        float s2 = dv * dv;
#pragma unroll
        for (int mm = 32; mm >= 1; mm >>= 1) s2 += __shfl_xor(s2, mm, 64);
        const float var = s2 * (1.f / 64.f);
        out[(size_t)n * 64 + lane] = dv * rsqrtf(var + LN_EPS) * gm + bt;
    }
}

// ---------------------------------------------------------------------------
extern "C" void kernel_launch(void* const* d_in, const int* in_sizes, int n_in,
                              void* d_out, int out_size, void* d_ws, size_t ws_size,
                              hipStream_t stream) {
    const float* x     = (const float*)d_in[0];
    const float* bases = (const float*)d_in[1];
    const float* comp  = (const float*)d_in[2];
    const float* loopw = (const float*)d_in[3];
    const float* bias  = (const float*)d_in[4];
    const float* gamma = (const float*)d_in[5];
    const float* beta  = (const float*)d_in[6];
    const int*   src   = (const int*)d_in[7];
    const int*   dst   = (const int*)d_in[8];
    const int*   et    = (const int*)d_in[9];
    float* out = (float*)d_out;

    size_t p = 0;
    auto alloc = [&](size_t bytes) {
        size_t cur = p;
        p = (p + bytes + 255) & ~(size_t)255;
        return cur;
    };
    char* ws = (char*)d_ws;
    const size_t o_counts = alloc((size_t)NBINS * sizeof(u32));
    const size_t o_cursor = alloc((size_t)NBINS * sizeof(u32));
    const size_t zero_len = p - o_counts;
    const size_t o_wf     = alloc((size_t)20 * 2 * 64 * 8 * sizeof(u16)); // 40 KB
    const size_t o_hb     = alloc((size_t)N_NODES * 256 * sizeof(u16));   // 51.2 MB
    const size_t o_sl     = alloc((size_t)N_NODES * 64 * sizeof(float));  // 25.6 MB
    const size_t o_offs   = alloc((size_t)NBINS * sizeof(u32));
    const size_t o_bsums  = alloc(128 * sizeof(u32));
    const size_t o_boffs  = alloc(128 * sizeof(u32));
    const size_t o_packed = alloc((size_t)N_EDGES * sizeof(u32));         // 6.4 MB
    const size_t need = p;

    const int edge_blocks = (N_EDGES + 255) / 256;

    if (ws_size >= need) {
        u32* counts = (u32*)(ws + o_counts);
        u32* cursor = (u32*)(ws + o_cursor);
        u16* wfp    = (u16*)(ws + o_wf);
        u16* hb     = (u16*)(ws + o_hb);
        float* sl   = (float*)(ws + o_sl);
        u32* offs   = (u32*)(ws + o_offs);
        u32* bsums  = (u32*)(ws + o_bsums);
        u32* boffs  = (u32*)(ws + o_boffs);
        u32* packed = (u32*)(ws + o_packed);

        hipMemsetAsync(ws + o_counts, 0, zero_len, stream);
        k_prep_hist<<<1 + HIST_BLOCKS, 256, 0, stream>>>(
            bases, loopw, wfp, dst, counts);
        k_gemm<<<(N_NODES / 16 + 3) / 4, 256, 0, stream>>>(
            x, (const short8*)wfp, bias, hb, sl);
        const int scan_blocks = (NBINS + 1023) / 1024;  // 98
        k_scan_block<<<scan_blocks, 1024, 0, stream>>>(counts, offs, bsums);
        k_scan_sums<<<1, 128, 0, stream>>>(bsums, boffs, scan_blocks);
        k_scatter<<<edge_blocks, 256, 0, stream>>>(src, dst, et, offs, boffs,
                                                   cursor, packed);
        k_agg_final<<<2048, 256, 0, stream>>>(hb, (const float4*)comp, packed,
                                              offs, boffs, counts, sl,
                                              gamma, beta, out);
    } else {
        hipMemsetAsync(d_out, 0, (size_t)N_NODES * 64 * sizeof(float), stream);
        k_edge_direct<<<(N_EDGES + 3) / 4, 256, 0, stream>>>(
            x, bases, comp, src, dst, et, out);
        k_finalize<<<2048, 256, 0, stream>>>(x, loopw, bias, gamma, beta, out);
    }
}

// Round 6
// 264.788 us; speedup vs baseline: 2.0159x; 1.1447x over previous
//
#include <hip/hip_runtime.h>

#define N_NODES 100000
#define N_EDGES 1600000
#define NBINS   100000
#define LN_EPS  1e-5f

#define HIST_BLOCKS 1024
#define XB_BLOCKS   256

typedef unsigned int u32;
typedef unsigned short u16;
typedef __attribute__((ext_vector_type(8))) short short8;
typedef __attribute__((ext_vector_type(4))) float f32x4;

__device__ __forceinline__ u16 f2bf(float f) {
    u32 u = __float_as_uint(f);
    u32 r = (u + 0x7FFFu + ((u >> 16) & 1u)) >> 16;   // round-to-nearest-even
    return (u16)r;
}
__device__ __forceinline__ float bf2f(u16 h) {
    return __uint_as_float((u32)h << 16);
}

// ---------------------------------------------------------------------------
// Fused independent prep, one launch:
//   block 0:               Wf fragment table for the fused GEMM (40 KB)
//   blocks [1, 1+XB):      xb[n][i] = bf16(x[n][i])  (12.8 MB table)
//   blocks [1+XB, +HIST):  histogram of dst
// Combined weight W[320][64]: k<256 -> bases[k&3][k>>2][c]; k>=256 ->
// loopw[k-256][c].  Wf[ct][ks][l][j] = W[ks*32+(l>>4)*8+j][ct*16+(l&15)].
// ---------------------------------------------------------------------------
__global__ __launch_bounds__(256) void k_prep_hist(
    const float* __restrict__ x, const float* __restrict__ bases,
    const float* __restrict__ loopw,
    u16* __restrict__ wf, u16* __restrict__ xb,
    const int* __restrict__ dst, u32* __restrict__ counts)
{
    const int t = threadIdx.x;
    if (blockIdx.x == 0) {
        for (int idx = t; idx < 4 * 10 * 64 * 8; idx += 256) {
            const int j = idx & 7;
            const int l = (idx >> 3) & 63;
            const int rest = idx >> 9;
            const int ks = rest % 10;
            const int ct = rest / 10;
            const int k = ks * 32 + (l >> 4) * 8 + j;
            const int c = ct * 16 + (l & 15);
            float v;
            if (k < 256) v = bases[(k & 3) * 4096 + (k >> 2) * 64 + c];
            else         v = loopw[(k - 256) * 64 + c];
            wf[idx] = f2bf(v);
        }
    } else if (blockIdx.x <= XB_BLOCKS) {
        const int bb = blockIdx.x - 1;
        for (int i = bb * 256 + t; i < N_NODES * 16; i += XB_BLOCKS * 256) {
            const float4 v = ((const float4*)x)[i];
            uint2 w;
            w.x = (u32)f2bf(v.x) | ((u32)f2bf(v.y) << 16);
            w.y = (u32)f2bf(v.z) | ((u32)f2bf(v.w) << 16);
            ((uint2*)xb)[i] = w;
        }
    } else {
        const int bb = blockIdx.x - 1 - XB_BLOCKS;
        for (int e = bb * 256 + t; e < N_EDGES; e += HIST_BLOCKS * 256)
            atomicAdd(&counts[dst[e]], 1u);
    }
}

// ---------------------------------------------------------------------------
// Block-level exclusive scan via wave shuffles.
// ---------------------------------------------------------------------------
__global__ __launch_bounds__(1024) void k_scan_block(
    const u32* __restrict__ counts, u32* __restrict__ offs,
    u32* __restrict__ bsums)
{
    __shared__ u32 wsum[16];
    const int t = threadIdx.x;
    const int lane = t & 63, wid = t >> 6;
    const int idx = blockIdx.x * 1024 + t;
    const u32 v = (idx < NBINS) ? counts[idx] : 0u;
    u32 s = v;
#pragma unroll
    for (int off = 1; off < 64; off <<= 1) {
        u32 u = __shfl_up(s, off, 64);
        if (lane >= off) s += u;
    }
    if (lane == 63) wsum[wid] = s;
    __syncthreads();
    if (wid == 0) {
        u32 w = (lane < 16) ? wsum[lane] : 0u;
#pragma unroll
        for (int off = 1; off < 16; off <<= 1) {
            u32 u = __shfl_up(w, off, 64);
            if (lane >= off) w += u;
        }
        if (lane < 16) wsum[lane] = w;
    }
    __syncthreads();
    const u32 prefix = (wid > 0) ? wsum[wid - 1] : 0u;
    const u32 incl = s + prefix;
    if (idx < NBINS) offs[idx] = incl - v;
    if (t == 1023) bsums[blockIdx.x] = incl;
}

__global__ __launch_bounds__(128) void k_scan_sums(
    const u32* __restrict__ bsums, u32* __restrict__ boffs, int nb)
{
    __shared__ u32 s[128];
    const int t = threadIdx.x;
    u32 v = (t < nb) ? bsums[t] : 0u;
    s[t] = v;
    __syncthreads();
#pragma unroll
    for (int off = 1; off < 128; off <<= 1) {
        u32 xv = (t >= off) ? s[t - off] : 0u;
        __syncthreads();
        s[t] += xv;
        __syncthreads();
    }
    boffs[t] = s[t] - v;
}

__global__ __launch_bounds__(256) void k_scatter(
    const int* __restrict__ src, const int* __restrict__ dst,
    const int* __restrict__ et,
    const u32* __restrict__ offs, const u32* __restrict__ boffs,
    u32* __restrict__ cursor, u32* __restrict__ packed)
{
    int e = blockIdx.x * 256 + threadIdx.x;
    if (e >= N_EDGES) return;
    const int d = dst[e];
    u32 pos = offs[d] + boffs[d >> 10] + atomicAdd(&cursor[d], 1u);
    packed[pos] = (u32)src[e] | ((u32)et[e] << 20);
}

// ---------------------------------------------------------------------------
// Input-space aggregation: one wave per dst node, lane = input feature i.
// y_b[n][i] = sum_e comp[et_e][b] * xb[src_e][i]   (4 f32 acc per lane)
// gather = 128 B/edge from the 12.8 MB xb table (L2-friendly).
// y stored bf16 [N][256] with k = i*4+b (GEMM A-row layout).
// ---------------------------------------------------------------------------
__global__ __launch_bounds__(256) void k_agg(
    const u16* __restrict__ xb, const float4* __restrict__ comp,
    const u32* __restrict__ packed,
    const u32* __restrict__ offs, const u32* __restrict__ boffs,
    const u32* __restrict__ counts,
    uint2* __restrict__ y)           // [N*64] uint2 (= [N][256] bf16)
{
    const int t = threadIdx.x;
    const int lane = t & 63;
    const int wid = t >> 6;
    const int waves = gridDim.x * 4;
    const u16* xbl = xb + lane;

    for (int n0 = blockIdx.x * 4 + wid; n0 < N_NODES; n0 += waves) {
        const int n = __builtin_amdgcn_readfirstlane(n0);
        const u32 base = offs[n] + boffs[n >> 10];
        const u32 deg = counts[n];
        float a0 = 0.f, a1 = 0.f, a2 = 0.f, a3 = 0.f;
        u32 done = 0;
        while (done < deg) {
            u32 cnt = deg - done;
            if (cnt > 64u) cnt = 64u;
            const u32 li = ((u32)lane < cnt) ? (u32)lane : 0u;
            const u32 recs = packed[base + done + li];
            u32 k = 0;
            for (; k + 8 <= cnt; k += 8) {
                u32 rr[8];
#pragma unroll
                for (int q = 0; q < 8; ++q)
                    rr[q] = (u32)__builtin_amdgcn_readlane((int)recs, (int)(k + q));
                u16 hv[8];
#pragma unroll
                for (int q = 0; q < 8; ++q)
                    hv[q] = xbl[(size_t)(rr[q] & 0xFFFFFu) * 64];
                float4 cc[8];
#pragma unroll
                for (int q = 0; q < 8; ++q) cc[q] = comp[rr[q] >> 20];
#pragma unroll
                for (int q = 0; q < 8; ++q) {
                    const float xf = bf2f(hv[q]);
                    a0 = fmaf(cc[q].x, xf, a0);
                    a1 = fmaf(cc[q].y, xf, a1);
                    a2 = fmaf(cc[q].z, xf, a2);
                    a3 = fmaf(cc[q].w, xf, a3);
                }
            }
            for (; k < cnt; ++k) {
                const u32 r0 = (u32)__builtin_amdgcn_readlane((int)recs, (int)k);
                const float4 c0 = comp[r0 >> 20];
                const float xf = bf2f(xbl[(size_t)(r0 & 0xFFFFFu) * 64]);
                a0 = fmaf(c0.x, xf, a0);
                a1 = fmaf(c0.y, xf, a1);
                a2 = fmaf(c0.z, xf, a2);
                a3 = fmaf(c0.w, xf, a3);
            }
            done += cnt;
        }
        uint2 w;
        w.x = (u32)f2bf(a0) | ((u32)f2bf(a1) << 16);
        w.y = (u32)f2bf(a2) | ((u32)f2bf(a3) << 16);
        y[(size_t)n * 64 + lane] = w;
    }
}

// ---------------------------------------------------------------------------
// Fused GEMM + epilogue: [N,320]bf16 (y||xb) @ Wf[320,64]bf16, then
// +bias, LeakyReLU, LayerNorm (16-lane-group shfl reductions), write out.
// One wave per 16-row tile: 4 col-tiles x 10 k-steps = 40 MFMA.
// C/D layout: col = lane&15, row = (lane>>4)*4 + reg (HW-verified).
// ---------------------------------------------------------------------------
__global__ __launch_bounds__(256) void k_gemm_ln(
    const short8* __restrict__ yf,   // [N*32] (y rows: 32 short8)
    const short8* __restrict__ xbf,  // [N*8]  (xb rows: 8 short8)
    const short8* __restrict__ wf,   // [4][10][64]
    const float* __restrict__ bias, const float* __restrict__ gamma,
    const float* __restrict__ beta, float* __restrict__ out)
{
    const int lane = threadIdx.x & 63;
    const int wid = threadIdx.x >> 6;
    const int m = lane & 15, kg = lane >> 4;
    float bsv[4], gm[4], bt[4];
#pragma unroll
    for (int ct = 0; ct < 4; ++ct) {
        bsv[ct] = bias[ct * 16 + m];
        gm[ct] = gamma[ct * 16 + m];
        bt[ct] = beta[ct * 16 + m];
    }
    const int ntiles = N_NODES / 16;              // 6250 exact
    for (int tile = blockIdx.x * 4 + wid; tile < ntiles; tile += gridDim.x * 4) {
        const int base = tile * 16;
        const int row = base + m;
        short8 a[10];
#pragma unroll
        for (int ks = 0; ks < 8; ++ks)
            a[ks] = yf[(size_t)row * 32 + ks * 4 + kg];
        a[8] = xbf[(size_t)row * 8 + kg];
        a[9] = xbf[(size_t)row * 8 + 4 + kg];
        f32x4 acc[4];
#pragma unroll
        for (int ct = 0; ct < 4; ++ct) {
            acc[ct] = (f32x4){0.f, 0.f, 0.f, 0.f};
#pragma unroll
            for (int ks = 0; ks < 10; ++ks)
                acc[ct] = __builtin_amdgcn_mfma_f32_16x16x32_bf16(
                    a[ks], wf[(ct * 10 + ks) * 64 + lane], acc[ct], 0, 0, 0);
        }
        // bias + LeakyReLU
        float v[4][4];
#pragma unroll
        for (int ct = 0; ct < 4; ++ct)
#pragma unroll
            for (int r = 0; r < 4; ++r) {
                const float u = acc[ct][r] + bsv[ct];
                v[ct][r] = (u >= 0.f) ? u : 0.1f * u;
            }
        // LayerNorm per row (row = base + kg*4 + r; 64 cols live on the
        // 16 lanes sharing kg, 4 values each)
#pragma unroll
        for (int r = 0; r < 4; ++r) {
            float s1 = v[0][r] + v[1][r] + v[2][r] + v[3][r];
#pragma unroll
            for (int mk = 1; mk < 16; mk <<= 1) s1 += __shfl_xor(s1, mk, 64);
            const float mu = s1 * (1.f / 64.f);
            float s2 = 0.f;
#pragma unroll
            for (int ct = 0; ct < 4; ++ct) {
                const float d = v[ct][r] - mu;
                s2 += d * d;
            }
#pragma unroll
            for (int mk = 1; mk < 16; mk <<= 1) s2 += __shfl_xor(s2, mk, 64);
            const float rstd = rsqrtf(s2 * (1.f / 64.f) + LN_EPS);
            const int ro = base + kg * 4 + r;
#pragma unroll
            for (int ct = 0; ct < 4; ++ct)
                out[(size_t)ro * 64 + ct * 16 + m] =
                    (v[ct][r] - mu) * rstd * gm[ct] + bt[ct];
        }
    }
}

// ---------------------------------------------------------------------------
// Fallback (tiny ws): direct per-edge compute with atomics + separate finalize.
// ---------------------------------------------------------------------------
__global__ __launch_bounds__(256) void k_edge_direct(
    const float* __restrict__ x, const float* __restrict__ bases,
    const float* __restrict__ comp,
    const int* __restrict__ src, const int* __restrict__ dst,
    const int* __restrict__ et, float* __restrict__ agg)
{
    const int lane = threadIdx.x & 63;
    int e = blockIdx.x * 4 + (threadIdx.x >> 6);
    if (e >= N_EDGES) return;
    e = __builtin_amdgcn_readfirstlane(e);
    const int s = src[e], d = dst[e], r = et[e];
    const float4 c = *(const float4*)(comp + r * 4);
    const float* xr = x + (size_t)s * 64;
    float acc = 0.f;
    for (int i = 0; i < 64; ++i) {
        const float w = c.x * bases[i * 64 + lane]
                      + c.y * bases[4096 + i * 64 + lane]
                      + c.z * bases[8192 + i * 64 + lane]
                      + c.w * bases[12288 + i * 64 + lane];
        acc = fmaf(xr[i], w, acc);
    }
    atomicAdd(&agg[(size_t)d * 64 + lane], acc);
}

__global__ __launch_bounds__(256) void k_finalize(
    const float* __restrict__ x, const float* __restrict__ loopw,
    const float* __restrict__ bias, const float* __restrict__ gamma,
    const float* __restrict__ beta, float* __restrict__ out)
{
    const int t = threadIdx.x;
    const int lane = t & 63;
    const int wid = t >> 6;
    float wreg[64];
#pragma unroll
    for (int i = 0; i < 64; ++i)
        wreg[i] = loopw[i * 64 + lane];
    const float bs = bias[lane], gm = gamma[lane], bt = beta[lane];
    const int waves = gridDim.x * 4;
    for (int n = blockIdx.x * 4 + wid; n < N_NODES; n += waves) {
        float xv = x[(size_t)n * 64 + lane];
        const int xbv = __float_as_int(xv);
        float slv = bs;
#pragma unroll
        for (int i = 0; i < 64; ++i) {
            const float s = __int_as_float(__builtin_amdgcn_readlane(xbv, i));
            slv = fmaf(s, wreg[i], slv);
        }
        float v = out[(size_t)n * 64 + lane] + slv;
        v = (v >= 0.f) ? v : 0.1f * v;
        float s1 = v;
#pragma unroll
        for (int mm = 32; mm >= 1; mm >>= 1) s1 += __shfl_xor(s1, mm, 64);
        const float mu = s1 * (1.f / 64.f);
        const float dv = v - mu;
        float s2 = dv * dv;
#pragma unroll
        for (int mm = 32; mm >= 1; mm >>= 1) s2 += __shfl_xor(s2, mm, 64);
        const float var = s2 * (1.f / 64.f);
        out[(size_t)n * 64 + lane] = dv * rsqrtf(var + LN_EPS) * gm + bt;
    }
}

// ---------------------------------------------------------------------------
extern "C" void kernel_launch(void* const* d_in, const int* in_sizes, int n_in,
                              void* d_out, int out_size, void* d_ws, size_t ws_size,
                              hipStream_t stream) {
    const float* x     = (const float*)d_in[0];
    const float* bases = (const float*)d_in[1];
    const float* comp  = (const float*)d_in[2];
    const float* loopw = (const float*)d_in[3];
    const float* bias  = (const float*)d_in[4];
    const float* gamma = (const float*)d_in[5];
    const float* beta  = (const float*)d_in[6];
    const int*   src   = (const int*)d_in[7];
    const int*   dst   = (const int*)d_in[8];
    const int*   et    = (const int*)d_in[9];
    float* out = (float*)d_out;

    size_t p = 0;
    auto alloc = [&](size_t bytes) {
        size_t cur = p;
        p = (p + bytes + 255) & ~(size_t)255;
        return cur;
    };
    char* ws = (char*)d_ws;
    const size_t o_counts = alloc((size_t)NBINS * sizeof(u32));
    const size_t o_cursor = alloc((size_t)NBINS * sizeof(u32));
    const size_t zero_len = p - o_counts;
    const size_t o_wf     = alloc((size_t)4 * 10 * 64 * 8 * sizeof(u16));  // 40 KB
    const size_t o_xb     = alloc((size_t)N_NODES * 64 * sizeof(u16));     // 12.8 MB
    const size_t o_y      = alloc((size_t)N_NODES * 256 * sizeof(u16));    // 51.2 MB
    const size_t o_offs   = alloc((size_t)NBINS * sizeof(u32));
    const size_t o_bsums  = alloc(128 * sizeof(u32));
    const size_t o_boffs  = alloc(128 * sizeof(u32));
    const size_t o_packed = alloc((size_t)N_EDGES * sizeof(u32));          // 6.4 MB
    const size_t need = p;

    const int edge_blocks = (N_EDGES + 255) / 256;

    if (ws_size >= need) {
        u32* counts = (u32*)(ws + o_counts);
        u32* cursor = (u32*)(ws + o_cursor);
        u16* wfp    = (u16*)(ws + o_wf);
        u16* xb     = (u16*)(ws + o_xb);
        u16* y      = (u16*)(ws + o_y);
        u32* offs   = (u32*)(ws + o_offs);
        u32* bsums  = (u32*)(ws + o_bsums);
        u32* boffs  = (u32*)(ws + o_boffs);
        u32* packed = (u32*)(ws + o_packed);

        hipMemsetAsync(ws + o_counts, 0, zero_len, stream);
        k_prep_hist<<<1 + XB_BLOCKS + HIST_BLOCKS, 256, 0, stream>>>(
            x, bases, loopw, wfp, xb, dst, counts);
        const int scan_blocks = (NBINS + 1023) / 1024;  // 98
        k_scan_block<<<scan_blocks, 1024, 0, stream>>>(counts, offs, bsums);
        k_scan_sums<<<1, 128, 0, stream>>>(bsums, boffs, scan_blocks);
        k_scatter<<<edge_blocks, 256, 0, stream>>>(src, dst, et, offs, boffs,
                                                   cursor, packed);
        k_agg<<<2048, 256, 0, stream>>>(xb, (const float4*)comp, packed,
                                        offs, boffs, counts, (uint2*)y);
        k_gemm_ln<<<(N_NODES / 16 + 3) / 4, 256, 0, stream>>>(
            (const short8*)y, (const short8*)xb, (const short8*)wfp,
            bias, gamma, beta, out);
    } else {
        hipMemsetAsync(d_out, 0, (size_t)N_NODES * 64 * sizeof(float), stream);
        k_edge_direct<<<(N_EDGES + 3) / 4, 256, 0, stream>>>(
            x, bases, comp, src, dst, et, out);
        k_finalize<<<2048, 256, 0, stream>>>(x, loopw, bias, gamma, beta, out);
    }
}

// Round 8
// 243.062 us; speedup vs baseline: 2.1961x; 1.0894x over previous
//
#include <hip/hip_runtime.h>

#define N_NODES 100000
#define N_EDGES 1600000
#define NBINS   100000
#define LN_EPS  1e-5f

#define HIST_BLOCKS 1024        // 8 groups x 128
#define XB_BLOCKS   256
#define SE_BLOCKS   64
#define SCAT_BLOCKS 1024        // 8 groups x 128
#define RANGE_PER_GROUP 12500   // NBINS / 8

typedef unsigned int u32;
typedef unsigned short u16;
typedef __attribute__((ext_vector_type(8))) short short8;
typedef __attribute__((ext_vector_type(4))) float f32x4;

__device__ __forceinline__ u16 f2bf(float f) {
    u32 u = __float_as_uint(f);
    u32 r = (u + 0x7FFFu + ((u >> 16) & 1u)) >> 16;   // round-to-nearest-even
    return (u16)r;
}
__device__ __forceinline__ float bf2f(u16 h) {
    return __uint_as_float((u32)h << 16);
}

// ---------------------------------------------------------------------------
// Fused independent prep, one launch:
//   blocks [0, HIST):            XCD-partitioned histogram of dst
//   block  HIST:                 Wf fragment table (40 KB)
//   blocks (HIST, HIST+XB]:      xb[n][i] = bf16(x[n][i])
//   blocks (HIST+XB, +SE]:       se[e] = src|et<<20
// Histogram: group g = blockIdx&7 owns dst range [g*12500,(g+1)*12500); each
// group streams ALL of dst (coalesced int4) but only counts its own range ->
// counts lines are single-group-owned (local L2 atomics, no XCD ping-pong).
// ---------------------------------------------------------------------------
__global__ __launch_bounds__(256) void k_prep_hist(
    const float* __restrict__ x, const float* __restrict__ bases,
    const float* __restrict__ loopw,
    const int* __restrict__ src, const int* __restrict__ dst,
    const int* __restrict__ et,
    u16* __restrict__ wf, u16* __restrict__ xb, u32* __restrict__ se,
    u32* __restrict__ counts)
{
    const int t = threadIdx.x;
    if (blockIdx.x < HIST_BLOCKS) {
        const int grp = blockIdx.x & 7;
        const int lo = grp * RANGE_PER_GROUP, hi = lo + RANGE_PER_GROUP;
        const int ig = blockIdx.x >> 3;
        const int4* dst4 = (const int4*)dst;
        const int stride = (HIST_BLOCKS / 8) * 256;
        for (int i = ig * 256 + t; i < N_EDGES / 4; i += stride) {
            const int4 d4 = dst4[i];
#pragma unroll
            for (int q = 0; q < 4; ++q) {
                const int d = (q == 0) ? d4.x : (q == 1) ? d4.y
                            : (q == 2) ? d4.z : d4.w;
                if (d >= lo && d < hi) atomicAdd(&counts[d], 1u);
            }
        }
    } else if (blockIdx.x == HIST_BLOCKS) {
        for (int idx = t; idx < 4 * 10 * 64 * 8; idx += 256) {
            const int j = idx & 7;
            const int l = (idx >> 3) & 63;
            const int rest = idx >> 9;
            const int ks = rest % 10;
            const int ct = rest / 10;
            const int k = ks * 32 + (l >> 4) * 8 + j;
            const int c = ct * 16 + (l & 15);
            float v;
            if (k < 256) v = bases[(k & 3) * 4096 + (k >> 2) * 64 + c];
            else         v = loopw[(k - 256) * 64 + c];
            wf[idx] = f2bf(v);
        }
    } else if (blockIdx.x <= HIST_BLOCKS + XB_BLOCKS) {
        const int bb = blockIdx.x - HIST_BLOCKS - 1;
        for (int i = bb * 256 + t; i < N_NODES * 16; i += XB_BLOCKS * 256) {
            const float4 v = ((const float4*)x)[i];
            uint2 w;
            w.x = (u32)f2bf(v.x) | ((u32)f2bf(v.y) << 16);
            w.y = (u32)f2bf(v.z) | ((u32)f2bf(v.w) << 16);
            ((uint2*)xb)[i] = w;
        }
    } else {
        const int bb = blockIdx.x - HIST_BLOCKS - 1 - XB_BLOCKS;
        for (int e = bb * 256 + t; e < N_EDGES; e += SE_BLOCKS * 256)
            se[e] = (u32)src[e] | ((u32)et[e] << 20);
    }
}

// ---------------------------------------------------------------------------
// Block-level exclusive scan via wave shuffles.
// ---------------------------------------------------------------------------
__global__ __launch_bounds__(1024) void k_scan_block(
    const u32* __restrict__ counts, u32* __restrict__ offs,
    u32* __restrict__ bsums)
{
    __shared__ u32 wsum[16];
    const int t = threadIdx.x;
    const int lane = t & 63, wid = t >> 6;
    const int idx = blockIdx.x * 1024 + t;
    const u32 v = (idx < NBINS) ? counts[idx] : 0u;
    u32 s = v;
#pragma unroll
    for (int off = 1; off < 64; off <<= 1) {
        u32 u = __shfl_up(s, off, 64);
        if (lane >= off) s += u;
    }
    if (lane == 63) wsum[wid] = s;
    __syncthreads();
    if (wid == 0) {
        u32 w = (lane < 16) ? wsum[lane] : 0u;
#pragma unroll
        for (int off = 1; off < 16; off <<= 1) {
            u32 u = __shfl_up(w, off, 64);
            if (lane >= off) w += u;
        }
        if (lane < 16) wsum[lane] = w;
    }
    __syncthreads();
    const u32 prefix = (wid > 0) ? wsum[wid - 1] : 0u;
    const u32 incl = s + prefix;
    if (idx < NBINS) offs[idx] = incl - v;
    if (t == 1023) bsums[blockIdx.x] = incl;
}

__global__ __launch_bounds__(128) void k_scan_sums(
    const u32* __restrict__ bsums, u32* __restrict__ boffs, int nb)
{
    __shared__ u32 s[128];
    const int t = threadIdx.x;
    u32 v = (t < nb) ? bsums[t] : 0u;
    s[t] = v;
    __syncthreads();
#pragma unroll
    for (int off = 1; off < 128; off <<= 1) {
        u32 xv = (t >= off) ? s[t - off] : 0u;
        __syncthreads();
        s[t] += xv;
        __syncthreads();
    }
    boffs[t] = s[t] - v;
}

// Fold block offsets into offs -> offs becomes the final global exclusive
// start. offs is READ-ONLY from here on (replay-stable atomic discipline).
__global__ __launch_bounds__(256) void k_offs_final(
    u32* __restrict__ offs, const u32* __restrict__ boffs)
{
    const int i = blockIdx.x * 256 + threadIdx.x;
    if (i < NBINS) offs[i] += boffs[i >> 10];
}

// ---------------------------------------------------------------------------
// XCD-partitioned scatter. Group g = blockIdx&7 owns dst range
// [g*12500,(g+1)*12500): streams ALL dst+se (int4/uint4 coalesced), emits
// only its own range. pos = offs[d] + atomicAdd(&cursor[d],1) -- offs stays
// read-only; cursor lines are single-group-owned (local L2 atomics).
// ---------------------------------------------------------------------------
__global__ __launch_bounds__(256) void k_scatter(
    const int* __restrict__ dst, const u32* __restrict__ se,
    const u32* __restrict__ offs, u32* __restrict__ cursor,
    u32* __restrict__ packed)
{
    const int grp = blockIdx.x & 7;
    const int lo = grp * RANGE_PER_GROUP, hi = lo + RANGE_PER_GROUP;
    const int ig = blockIdx.x >> 3;
    const int4* dst4 = (const int4*)dst;
    const uint4* se4 = (const uint4*)se;
    const int stride = (SCAT_BLOCKS / 8) * 256;
    for (int i = ig * 256 + threadIdx.x; i < N_EDGES / 4; i += stride) {
        const int4 d4 = dst4[i];
        const uint4 s4 = se4[i];
#pragma unroll
        for (int q = 0; q < 4; ++q) {
            const int d = (q == 0) ? d4.x : (q == 1) ? d4.y
                        : (q == 2) ? d4.z : d4.w;
            const u32 sv = (q == 0) ? s4.x : (q == 1) ? s4.y
                         : (q == 2) ? s4.z : s4.w;
            if (d >= lo && d < hi) {
                const u32 pos = offs[d] + atomicAdd(&cursor[d], 1u);
                packed[pos] = sv;
            }
        }
    }
}

// ---------------------------------------------------------------------------
// Input-space aggregation: one wave per dst node, lane = input feature i.
// y_b[n][i] = sum_e comp[et_e][b] * xb[src_e][i]   (4 f32 acc per lane)
// Segment = [offs[n], offs[n]+counts[n]); offs never mutated.
// ---------------------------------------------------------------------------
__global__ __launch_bounds__(256) void k_agg(
    const u16* __restrict__ xb, const float4* __restrict__ comp,
    const u32* __restrict__ packed,
    const u32* __restrict__ offs, const u32* __restrict__ counts,
    uint2* __restrict__ y)           // [N*64] uint2 (= [N][256] bf16)
{
    const int t = threadIdx.x;
    const int lane = t & 63;
    const int wid = t >> 6;
    const int waves = gridDim.x * 4;
    const u16* xbl = xb + lane;

    for (int n0 = blockIdx.x * 4 + wid; n0 < N_NODES; n0 += waves) {
        const int n = __builtin_amdgcn_readfirstlane(n0);
        const u32 deg = counts[n];
        const u32 base = offs[n];
        float a0 = 0.f, a1 = 0.f, a2 = 0.f, a3 = 0.f;
        u32 done = 0;
        while (done < deg) {
            u32 cnt = deg - done;
            if (cnt > 64u) cnt = 64u;
            const u32 li = ((u32)lane < cnt) ? (u32)lane : 0u;
            const u32 recs = packed[base + done + li];
            u32 k = 0;
            for (; k + 8 <= cnt; k += 8) {
                u32 rr[8];
#pragma unroll
                for (int q = 0; q < 8; ++q)
                    rr[q] = (u32)__builtin_amdgcn_readlane((int)recs, (int)(k + q));
                u16 hv[8];
#pragma unroll
                for (int q = 0; q < 8; ++q)
                    hv[q] = xbl[(size_t)(rr[q] & 0xFFFFFu) * 64];
                float4 cc[8];
#pragma unroll
                for (int q = 0; q < 8; ++q) cc[q] = comp[rr[q] >> 20];
#pragma unroll
                for (int q = 0; q < 8; ++q) {
                    const float xf = bf2f(hv[q]);
                    a0 = fmaf(cc[q].x, xf, a0);
                    a1 = fmaf(cc[q].y, xf, a1);
                    a2 = fmaf(cc[q].z, xf, a2);
                    a3 = fmaf(cc[q].w, xf, a3);
                }
            }
            for (; k < cnt; ++k) {
                const u32 r0 = (u32)__builtin_amdgcn_readlane((int)recs, (int)k);
                const float4 c0 = comp[r0 >> 20];
                const float xf = bf2f(xbl[(size_t)(r0 & 0xFFFFFu) * 64]);
                a0 = fmaf(c0.x, xf, a0);
                a1 = fmaf(c0.y, xf, a1);
                a2 = fmaf(c0.z, xf, a2);
                a3 = fmaf(c0.w, xf, a3);
            }
            done += cnt;
        }
        uint2 w;
        w.x = (u32)f2bf(a0) | ((u32)f2bf(a1) << 16);
        w.y = (u32)f2bf(a2) | ((u32)f2bf(a3) << 16);
        y[(size_t)n * 64 + lane] = w;
    }
}

// ---------------------------------------------------------------------------
// Fused GEMM + epilogue: [N,320]bf16 (y||xb) @ Wf[320,64]bf16, then
// +bias, LeakyReLU, LayerNorm (16-lane-group shfl reductions), write out.
// ---------------------------------------------------------------------------
__global__ __launch_bounds__(256) void k_gemm_ln(
    const short8* __restrict__ yf,   // [N*32]
    const short8* __restrict__ xbf,  // [N*8]
    const short8* __restrict__ wf,   // [4][10][64]
    const float* __restrict__ bias, const float* __restrict__ gamma,
    const float* __restrict__ beta, float* __restrict__ out)
{
    const int lane = threadIdx.x & 63;
    const int wid = threadIdx.x >> 6;
    const int m = lane & 15, kg = lane >> 4;
    float bsv[4], gm[4], bt[4];
#pragma unroll
    for (int ct = 0; ct < 4; ++ct) {
        bsv[ct] = bias[ct * 16 + m];
        gm[ct] = gamma[ct * 16 + m];
        bt[ct] = beta[ct * 16 + m];
    }
    const int ntiles = N_NODES / 16;              // 6250 exact
    for (int tile = blockIdx.x * 4 + wid; tile < ntiles; tile += gridDim.x * 4) {
        const int base = tile * 16;
        const int row = base + m;
        short8 a[10];
#pragma unroll
        for (int ks = 0; ks < 8; ++ks)
            a[ks] = yf[(size_t)row * 32 + ks * 4 + kg];
        a[8] = xbf[(size_t)row * 8 + kg];
        a[9] = xbf[(size_t)row * 8 + 4 + kg];
        f32x4 acc[4];
#pragma unroll
        for (int ct = 0; ct < 4; ++ct) {
            acc[ct] = (f32x4){0.f, 0.f, 0.f, 0.f};
#pragma unroll
            for (int ks = 0; ks < 10; ++ks)
                acc[ct] = __builtin_amdgcn_mfma_f32_16x16x32_bf16(
                    a[ks], wf[(ct * 10 + ks) * 64 + lane], acc[ct], 0, 0, 0);
        }
        float v[4][4];
#pragma unroll
        for (int ct = 0; ct < 4; ++ct)
#pragma unroll
            for (int r = 0; r < 4; ++r) {
                const float u = acc[ct][r] + bsv[ct];
                v[ct][r] = (u >= 0.f) ? u : 0.1f * u;
            }
#pragma unroll
        for (int r = 0; r < 4; ++r) {
            float s1 = v[0][r] + v[1][r] + v[2][r] + v[3][r];
#pragma unroll
            for (int mk = 1; mk < 16; mk <<= 1) s1 += __shfl_xor(s1, mk, 64);
            const float mu = s1 * (1.f / 64.f);
            float s2 = 0.f;
#pragma unroll
            for (int ct = 0; ct < 4; ++ct) {
                const float d = v[ct][r] - mu;
                s2 += d * d;
            }
#pragma unroll
            for (int mk = 1; mk < 16; mk <<= 1) s2 += __shfl_xor(s2, mk, 64);
            const float rstd = rsqrtf(s2 * (1.f / 64.f) + LN_EPS);
            const int ro = base + kg * 4 + r;
#pragma unroll
            for (int ct = 0; ct < 4; ++ct)
                out[(size_t)ro * 64 + ct * 16 + m] =
                    (v[ct][r] - mu) * rstd * gm[ct] + bt[ct];
        }
    }
}

// ---------------------------------------------------------------------------
// Fallback (tiny ws): direct per-edge compute with atomics + separate finalize.
// ---------------------------------------------------------------------------
__global__ __launch_bounds__(256) void k_edge_direct(
    const float* __restrict__ x, const float* __restrict__ bases,
    const float* __restrict__ comp,
    const int* __restrict__ src, const int* __restrict__ dst,
    const int* __restrict__ et, float* __restrict__ agg)
{
    const int lane = threadIdx.x & 63;
    int e = blockIdx.x * 4 + (threadIdx.x >> 6);
    if (e >= N_EDGES) return;
    e = __builtin_amdgcn_readfirstlane(e);
    const int s = src[e], d = dst[e], r = et[e];
    const float4 c = *(const float4*)(comp + r * 4);
    const float* xr = x + (size_t)s * 64;
    float acc = 0.f;
    for (int i = 0; i < 64; ++i) {
        const float w = c.x * bases[i * 64 + lane]
                      + c.y * bases[4096 + i * 64 + lane]
                      + c.z * bases[8192 + i * 64 + lane]
                      + c.w * bases[12288 + i * 64 + lane];
        acc = fmaf(xr[i], w, acc);
    }
    atomicAdd(&agg[(size_t)d * 64 + lane], acc);
}

__global__ __launch_bounds__(256) void k_finalize(
    const float* __restrict__ x, const float* __restrict__ loopw,
    const float* __restrict__ bias, const float* __restrict__ gamma,
    const float* __restrict__ beta, float* __restrict__ out)
{
    const int t = threadIdx.x;
    const int lane = t & 63;
    const int wid = t >> 6;
    float wreg[64];
#pragma unroll
    for (int i = 0; i < 64; ++i)
        wreg[i] = loopw[i * 64 + lane];
    const float bs = bias[lane], gm = gamma[lane], bt = beta[lane];
    const int waves = gridDim.x * 4;
    for (int n = blockIdx.x * 4 + wid; n < N_NODES; n += waves) {
        float xv = x[(size_t)n * 64 + lane];
        const int xbv = __float_as_int(xv);
        float slv = bs;
#pragma unroll
        for (int i = 0; i < 64; ++i) {
            const float s = __int_as_float(__builtin_amdgcn_readlane(xbv, i));
            slv = fmaf(s, wreg[i], slv);
        }
        float v = out[(size_t)n * 64 + lane] + slv;
        v = (v >= 0.f) ? v : 0.1f * v;
        float s1 = v;
#pragma unroll
        for (int mm = 32; mm >= 1; mm >>= 1) s1 += __shfl_xor(s1, mm, 64);
        const float mu = s1 * (1.f / 64.f);
        const float dv = v - mu;
        float s2 = dv * dv;
#pragma unroll
        for (int mm = 32; mm >= 1; mm >>= 1) s2 += __shfl_xor(s2, mm, 64);
        const float var = s2 * (1.f / 64.f);
        out[(size_t)n * 64 + lane] = dv * rsqrtf(var + LN_EPS) * gm + bt;
    }
}

// ---------------------------------------------------------------------------
extern "C" void kernel_launch(void* const* d_in, const int* in_sizes, int n_in,
                              void* d_out, int out_size, void* d_ws, size_t ws_size,
                              hipStream_t stream) {
    const float* x     = (const float*)d_in[0];
    const float* bases = (const float*)d_in[1];
    const float* comp  = (const float*)d_in[2];
    const float* loopw = (const float*)d_in[3];
    const float* bias  = (const float*)d_in[4];
    const float* gamma = (const float*)d_in[5];
    const float* beta  = (const float*)d_in[6];
    const int*   src   = (const int*)d_in[7];
    const int*   dst   = (const int*)d_in[8];
    const int*   et    = (const int*)d_in[9];
    float* out = (float*)d_out;

    size_t p = 0;
    auto alloc = [&](size_t bytes) {
        size_t cur = p;
        p = (p + bytes + 255) & ~(size_t)255;
        return cur;
    };
    char* ws = (char*)d_ws;
    const size_t o_counts = alloc((size_t)NBINS * sizeof(u32));
    const size_t o_cursor = alloc((size_t)NBINS * sizeof(u32));
    const size_t zero_len = p - o_counts;   // counts + cursor in one memset
    const size_t o_wf     = alloc((size_t)4 * 10 * 64 * 8 * sizeof(u16));  // 40 KB
    const size_t o_xb     = alloc((size_t)N_NODES * 64 * sizeof(u16));     // 12.8 MB
    const size_t o_y      = alloc((size_t)N_NODES * 256 * sizeof(u16));    // 51.2 MB
    const size_t o_se     = alloc((size_t)N_EDGES * sizeof(u32));          // 6.4 MB
    const size_t o_offs   = alloc((size_t)NBINS * sizeof(u32));
    const size_t o_bsums  = alloc(128 * sizeof(u32));
    const size_t o_boffs  = alloc(128 * sizeof(u32));
    const size_t o_packed = alloc((size_t)N_EDGES * sizeof(u32));          // 6.4 MB
    const size_t need = p;

    if (ws_size >= need) {
        u32* counts = (u32*)(ws + o_counts);
        u32* cursor = (u32*)(ws + o_cursor);
        u16* wfp    = (u16*)(ws + o_wf);
        u16* xb     = (u16*)(ws + o_xb);
        u16* y      = (u16*)(ws + o_y);
        u32* se     = (u32*)(ws + o_se);
        u32* offs   = (u32*)(ws + o_offs);
        u32* bsums  = (u32*)(ws + o_bsums);
        u32* boffs  = (u32*)(ws + o_boffs);
        u32* packed = (u32*)(ws + o_packed);

        hipMemsetAsync(ws + o_counts, 0, zero_len, stream);
        k_prep_hist<<<HIST_BLOCKS + 1 + XB_BLOCKS + SE_BLOCKS, 256, 0, stream>>>(
            x, bases, loopw, src, dst, et, wfp, xb, se, counts);
        const int scan_blocks = (NBINS + 1023) / 1024;  // 98
        k_scan_block<<<scan_blocks, 1024, 0, stream>>>(counts, offs, bsums);
        k_scan_sums<<<1, 128, 0, stream>>>(bsums, boffs, scan_blocks);
        k_offs_final<<<(NBINS + 255) / 256, 256, 0, stream>>>(offs, boffs);
        k_scatter<<<SCAT_BLOCKS, 256, 0, stream>>>(dst, se, offs, cursor, packed);
        k_agg<<<2048, 256, 0, stream>>>(xb, (const float4*)comp, packed,
                                        offs, counts, (uint2*)y);
        k_gemm_ln<<<(N_NODES / 16 + 3) / 4, 256, 0, stream>>>(
            (const short8*)y, (const short8*)xb, (const short8*)wfp,
            bias, gamma, beta, out);
    } else {
        hipMemsetAsync(d_out, 0, (size_t)N_NODES * 64 * sizeof(float), stream);
        k_edge_direct<<<(N_EDGES + 3) / 4, 256, 0, stream>>>(
            x, bases, comp, src, dst, et, out);
        k_finalize<<<2048, 256, 0, stream>>>(x, loopw, bias, gamma, beta, out);
    }
}

// Round 9
// 179.606 us; speedup vs baseline: 2.9720x; 1.3533x over previous
//
#include <hip/hip_runtime.h>

#define N_NODES 100000
#define N_EDGES 1600000
#define NBINS   100000
#define LN_EPS  1e-5f

#define NG 8                 // range groups
#define NS 32                // edge slices
#define RANGE 12500          // NBINS / NG
#define SLICE_I4 12500       // (N_EDGES/4) / NS

#define XB_BLOCKS   256
#define SE_BLOCKS   64

typedef unsigned int u32;
typedef unsigned short u16;
typedef __attribute__((ext_vector_type(8))) short short8;
typedef __attribute__((ext_vector_type(4))) float f32x4;

__device__ __forceinline__ u16 f2bf(float f) {
    u32 u = __float_as_uint(f);
    u32 r = (u + 0x7FFFu + ((u >> 16) & 1u)) >> 16;   // round-to-nearest-even
    return (u16)r;
}
__device__ __forceinline__ float bf2f(u16 h) {
    return __uint_as_float((u32)h << 16);
}

// ---------------------------------------------------------------------------
// Fused prep (no atomics): block 0 = Wf table; [1,XB] = xb bf16 cast;
// (XB, XB+SE] = se[e] = src|et<<20.
// ---------------------------------------------------------------------------
__global__ __launch_bounds__(256) void k_prep(
    const float* __restrict__ x, const float* __restrict__ bases,
    const float* __restrict__ loopw,
    const int* __restrict__ src, const int* __restrict__ et,
    u16* __restrict__ wf, u16* __restrict__ xb, u32* __restrict__ se)
{
    const int t = threadIdx.x;
    if (blockIdx.x == 0) {
        for (int idx = t; idx < 4 * 10 * 64 * 8; idx += 256) {
            const int j = idx & 7;
            const int l = (idx >> 3) & 63;
            const int rest = idx >> 9;
            const int ks = rest % 10;
            const int ct = rest / 10;
            const int k = ks * 32 + (l >> 4) * 8 + j;
            const int c = ct * 16 + (l & 15);
            float v;
            if (k < 256) v = bases[(k & 3) * 4096 + (k >> 2) * 64 + c];
            else         v = loopw[(k - 256) * 64 + c];
            wf[idx] = f2bf(v);
        }
    } else if (blockIdx.x <= XB_BLOCKS) {
        const int bb = blockIdx.x - 1;
        for (int i = bb * 256 + t; i < N_NODES * 16; i += XB_BLOCKS * 256) {
            const float4 v = ((const float4*)x)[i];
            uint2 w;
            w.x = (u32)f2bf(v.x) | ((u32)f2bf(v.y) << 16);
            w.y = (u32)f2bf(v.z) | ((u32)f2bf(v.w) << 16);
            ((uint2*)xb)[i] = w;
        }
    } else {
        const int bb = blockIdx.x - 1 - XB_BLOCKS;
        for (int e = bb * 256 + t; e < N_EDGES; e += SE_BLOCKS * 256)
            se[e] = (u32)src[e] | ((u32)et[e] << 20);
    }
}

// ---------------------------------------------------------------------------
// LDS-privatized histogram: block (g,s) counts slice s of edges into a 50 KB
// LDS histogram of range g, then writes its private slice with plain stores.
// Zero global atomics; LDS ds_add doesn't serialize the vmcnt queue.
// ---------------------------------------------------------------------------
__global__ __launch_bounds__(256) void k_hist(
    const int* __restrict__ dst, u32* __restrict__ priv)
{
    __shared__ u32 lh[RANGE];
    const int t = threadIdx.x;
    for (int j = t; j < RANGE; j += 256) lh[j] = 0u;
    __syncthreads();
    const int g = blockIdx.x & (NG - 1);
    const int s = blockIdx.x >> 3;
    const int lo = g * RANGE;
    const int4* dst4 = (const int4*)dst;
    const int i0 = s * SLICE_I4;
    for (int i = i0 + t; i < i0 + SLICE_I4; i += 256) {
        const int4 d4 = dst4[i];
#pragma unroll
        for (int q = 0; q < 4; ++q) {
            const int d = (q == 0) ? d4.x : (q == 1) ? d4.y
                        : (q == 2) ? d4.z : d4.w;
            const u32 rel = (u32)(d - lo);
            if (rel < (u32)RANGE) atomicAdd(&lh[rel], 1u);
        }
    }
    __syncthreads();
    u32* pb = priv + (size_t)(g * NS + s) * RANGE;
    for (int j = t; j < RANGE; j += 256) pb[j] = lh[j];
}

// ---------------------------------------------------------------------------
// Scan: per bin, sum the 32 private slices -> counts; block-exclusive scan ->
// offs (local); write back per-slice running prefixes into priv (local).
// ---------------------------------------------------------------------------
__global__ __launch_bounds__(1024) void k_scan_block(
    u32* __restrict__ priv, u32* __restrict__ counts,
    u32* __restrict__ offs, u32* __restrict__ bsums)
{
    __shared__ u32 wsum[16];
    const int t = threadIdx.x;
    const int lane = t & 63, wid = t >> 6;
    const int idx = blockIdx.x * 1024 + t;
    u32 sv[NS];
    u32 v = 0u;
    u32 g = 0, local = 0;
    if (idx < NBINS) {
        g = (u32)idx / (u32)RANGE;
        local = (u32)idx - g * (u32)RANGE;
#pragma unroll
        for (int s = 0; s < NS; ++s) {
            sv[s] = priv[(size_t)(g * NS + s) * RANGE + local];
            v += sv[s];
        }
    }
    u32 sc = v;
#pragma unroll
    for (int off = 1; off < 64; off <<= 1) {
        u32 u = __shfl_up(sc, off, 64);
        if (lane >= off) sc += u;
    }
    if (lane == 63) wsum[wid] = sc;
    __syncthreads();
    if (wid == 0) {
        u32 w = (lane < 16) ? wsum[lane] : 0u;
#pragma unroll
        for (int off = 1; off < 16; off <<= 1) {
            u32 u = __shfl_up(w, off, 64);
            if (lane >= off) w += u;
        }
        if (lane < 16) wsum[lane] = w;
    }
    __syncthreads();
    const u32 prefix = (wid > 0) ? wsum[wid - 1] : 0u;
    const u32 incl = sc + prefix;
    const u32 excl = incl - v;
    if (idx < NBINS) {
        offs[idx] = excl;
        counts[idx] = v;
        u32 run = excl;
#pragma unroll
        for (int s = 0; s < NS; ++s) {
            priv[(size_t)(g * NS + s) * RANGE + local] = run;
            run += sv[s];
        }
    }
    if (t == 1023) bsums[blockIdx.x] = incl;
}

__global__ __launch_bounds__(128) void k_scan_sums(
    const u32* __restrict__ bsums, u32* __restrict__ boffs, int nb)
{
    __shared__ u32 s[128];
    const int t = threadIdx.x;
    u32 v = (t < nb) ? bsums[t] : 0u;
    s[t] = v;
    __syncthreads();
#pragma unroll
    for (int off = 1; off < 128; off <<= 1) {
        u32 xv = (t >= off) ? s[t - off] : 0u;
        __syncthreads();
        s[t] += xv;
        __syncthreads();
    }
    boffs[t] = s[t] - v;
}

// offs += boffs -> final global exclusive starts. offs read-only afterwards.
__global__ __launch_bounds__(256) void k_offs_final(
    u32* __restrict__ offs, const u32* __restrict__ boffs)
{
    const int i = blockIdx.x * 256 + threadIdx.x;
    if (i < NBINS) offs[i] += boffs[i >> 10];
}

// ---------------------------------------------------------------------------
// Scatter with LDS cursors: block (g,s) seeds cursors = priv[g][s][:] + boffs,
// streams its slice, ranks via LDS atomics, plain-stores packed records.
// No global atomics; offs/priv are read-only here.
// ---------------------------------------------------------------------------
__global__ __launch_bounds__(256) void k_scatter(
    const int* __restrict__ dst, const u32* __restrict__ se,
    const u32* __restrict__ priv, const u32* __restrict__ boffs,
    u32* __restrict__ packed)
{
    __shared__ u32 cur[RANGE];
    const int t = threadIdx.x;
    const int g = blockIdx.x & (NG - 1);
    const int s = blockIdx.x >> 3;
    const int lo = g * RANGE;
    const u32* pb = priv + (size_t)(g * NS + s) * RANGE;
    for (int j = t; j < RANGE; j += 256)
        cur[j] = pb[j] + boffs[(lo + j) >> 10];
    __syncthreads();
    const int4* dst4 = (const int4*)dst;
    const uint4* se4 = (const uint4*)se;
    const int i0 = s * SLICE_I4;
    for (int i = i0 + t; i < i0 + SLICE_I4; i += 256) {
        const int4 d4 = dst4[i];
        const uint4 s4 = se4[i];
#pragma unroll
        for (int q = 0; q < 4; ++q) {
            const int d = (q == 0) ? d4.x : (q == 1) ? d4.y
                        : (q == 2) ? d4.z : d4.w;
            const u32 sv = (q == 0) ? s4.x : (q == 1) ? s4.y
                         : (q == 2) ? s4.z : s4.w;
            const u32 rel = (u32)(d - lo);
            if (rel < (u32)RANGE) {
                const u32 pos = atomicAdd(&cur[rel], 1u);
                packed[pos] = sv;
            }
        }
    }
}

// ---------------------------------------------------------------------------
// Input-space aggregation: one wave per dst node, lane = input feature i.
// y_b[n][i] = sum_e comp[et_e][b] * xb[src_e][i]   (4 f32 acc per lane)
// Segment = [offs[n], offs[n]+counts[n]); offs never mutated.
// ---------------------------------------------------------------------------
__global__ __launch_bounds__(256) void k_agg(
    const u16* __restrict__ xb, const float4* __restrict__ comp,
    const u32* __restrict__ packed,
    const u32* __restrict__ offs, const u32* __restrict__ counts,
    uint2* __restrict__ y)           // [N*64] uint2 (= [N][256] bf16)
{
    const int t = threadIdx.x;
    const int lane = t & 63;
    const int wid = t >> 6;
    const int waves = gridDim.x * 4;
    const u16* xbl = xb + lane;

    for (int n0 = blockIdx.x * 4 + wid; n0 < N_NODES; n0 += waves) {
        const int n = __builtin_amdgcn_readfirstlane(n0);
        const u32 deg = counts[n];
        const u32 base = offs[n];
        float a0 = 0.f, a1 = 0.f, a2 = 0.f, a3 = 0.f;
        u32 done = 0;
        while (done < deg) {
            u32 cnt = deg - done;
            if (cnt > 64u) cnt = 64u;
            const u32 li = ((u32)lane < cnt) ? (u32)lane : 0u;
            const u32 recs = packed[base + done + li];
            u32 k = 0;
            for (; k + 8 <= cnt; k += 8) {
                u32 rr[8];
#pragma unroll
                for (int q = 0; q < 8; ++q)
                    rr[q] = (u32)__builtin_amdgcn_readlane((int)recs, (int)(k + q));
                u16 hv[8];
#pragma unroll
                for (int q = 0; q < 8; ++q)
                    hv[q] = xbl[(size_t)(rr[q] & 0xFFFFFu) * 64];
                float4 cc[8];
#pragma unroll
                for (int q = 0; q < 8; ++q) cc[q] = comp[rr[q] >> 20];
#pragma unroll
                for (int q = 0; q < 8; ++q) {
                    const float xf = bf2f(hv[q]);
                    a0 = fmaf(cc[q].x, xf, a0);
                    a1 = fmaf(cc[q].y, xf, a1);
                    a2 = fmaf(cc[q].z, xf, a2);
                    a3 = fmaf(cc[q].w, xf, a3);
                }
            }
            for (; k < cnt; ++k) {
                const u32 r0 = (u32)__builtin_amdgcn_readlane((int)recs, (int)k);
                const float4 c0 = comp[r0 >> 20];
                const float xf = bf2f(xbl[(size_t)(r0 & 0xFFFFFu) * 64]);
                a0 = fmaf(c0.x, xf, a0);
                a1 = fmaf(c0.y, xf, a1);
                a2 = fmaf(c0.z, xf, a2);
                a3 = fmaf(c0.w, xf, a3);
            }
            done += cnt;
        }
        uint2 w;
        w.x = (u32)f2bf(a0) | ((u32)f2bf(a1) << 16);
        w.y = (u32)f2bf(a2) | ((u32)f2bf(a3) << 16);
        y[(size_t)n * 64 + lane] = w;
    }
}

// ---------------------------------------------------------------------------
// Fused GEMM + epilogue: [N,320]bf16 (y||xb) @ Wf[320,64]bf16, then
// +bias, LeakyReLU, LayerNorm (16-lane-group shfl reductions), write out.
// ---------------------------------------------------------------------------
__global__ __launch_bounds__(256) void k_gemm_ln(
    const short8* __restrict__ yf,   // [N*32]
    const short8* __restrict__ xbf,  // [N*8]
    const short8* __restrict__ wf,   // [4][10][64]
    const float* __restrict__ bias, const float* __restrict__ gamma,
    const float* __restrict__ beta, float* __restrict__ out)
{
    const int lane = threadIdx.x & 63;
    const int wid = threadIdx.x >> 6;
    const int m = lane & 15, kg = lane >> 4;
    float bsv[4], gm[4], bt[4];
#pragma unroll
    for (int ct = 0; ct < 4; ++ct) {
        bsv[ct] = bias[ct * 16 + m];
        gm[ct] = gamma[ct * 16 + m];
        bt[ct] = beta[ct * 16 + m];
    }
    const int ntiles = N_NODES / 16;              // 6250 exact
    for (int tile = blockIdx.x * 4 + wid; tile < ntiles; tile += gridDim.x * 4) {
        const int base = tile * 16;
        const int row = base + m;
        short8 a[10];
#pragma unroll
        for (int ks = 0; ks < 8; ++ks)
            a[ks] = yf[(size_t)row * 32 + ks * 4 + kg];
        a[8] = xbf[(size_t)row * 8 + kg];
        a[9] = xbf[(size_t)row * 8 + 4 + kg];
        f32x4 acc[4];
#pragma unroll
        for (int ct = 0; ct < 4; ++ct) {
            acc[ct] = (f32x4){0.f, 0.f, 0.f, 0.f};
#pragma unroll
            for (int ks = 0; ks < 10; ++ks)
                acc[ct] = __builtin_amdgcn_mfma_f32_16x16x32_bf16(
                    a[ks], wf[(ct * 10 + ks) * 64 + lane], acc[ct], 0, 0, 0);
        }
        float v[4][4];
#pragma unroll
        for (int ct = 0; ct < 4; ++ct)
#pragma unroll
            for (int r = 0; r < 4; ++r) {
                const float u = acc[ct][r] + bsv[ct];
                v[ct][r] = (u >= 0.f) ? u : 0.1f * u;
            }
#pragma unroll
        for (int r = 0; r < 4; ++r) {
            float s1 = v[0][r] + v[1][r] + v[2][r] + v[3][r];
#pragma unroll
            for (int mk = 1; mk < 16; mk <<= 1) s1 += __shfl_xor(s1, mk, 64);
            const float mu = s1 * (1.f / 64.f);
            float s2 = 0.f;
#pragma unroll
            for (int ct = 0; ct < 4; ++ct) {
                const float d = v[ct][r] - mu;
                s2 += d * d;
            }
#pragma unroll
            for (int mk = 1; mk < 16; mk <<= 1) s2 += __shfl_xor(s2, mk, 64);
            const float rstd = rsqrtf(s2 * (1.f / 64.f) + LN_EPS);
            const int ro = base + kg * 4 + r;
#pragma unroll
            for (int ct = 0; ct < 4; ++ct)
                out[(size_t)ro * 64 + ct * 16 + m] =
                    (v[ct][r] - mu) * rstd * gm[ct] + bt[ct];
        }
    }
}

// ---------------------------------------------------------------------------
// Fallback (tiny ws): direct per-edge compute with atomics + separate finalize.
// ---------------------------------------------------------------------------
__global__ __launch_bounds__(256) void k_edge_direct(
    const float* __restrict__ x, const float* __restrict__ bases,
    const float* __restrict__ comp,
    const int* __restrict__ src, const int* __restrict__ dst,
    const int* __restrict__ et, float* __restrict__ agg)
{
    const int lane = threadIdx.x & 63;
    int e = blockIdx.x * 4 + (threadIdx.x >> 6);
    if (e >= N_EDGES) return;
    e = __builtin_amdgcn_readfirstlane(e);
    const int s = src[e], d = dst[e], r = et[e];
    const float4 c = *(const float4*)(comp + r * 4);
    const float* xr = x + (size_t)s * 64;
    float acc = 0.f;
    for (int i = 0; i < 64; ++i) {
        const float w = c.x * bases[i * 64 + lane]
                      + c.y * bases[4096 + i * 64 + lane]
                      + c.z * bases[8192 + i * 64 + lane]
                      + c.w * bases[12288 + i * 64 + lane];
        acc = fmaf(xr[i], w, acc);
    }
    atomicAdd(&agg[(size_t)d * 64 + lane], acc);
}

__global__ __launch_bounds__(256) void k_finalize(
    const float* __restrict__ x, const float* __restrict__ loopw,
    const float* __restrict__ bias, const float* __restrict__ gamma,
    const float* __restrict__ beta, float* __restrict__ out)
{
    const int t = threadIdx.x;
    const int lane = t & 63;
    const int wid = t >> 6;
    float wreg[64];
#pragma unroll
    for (int i = 0; i < 64; ++i)
        wreg[i] = loopw[i * 64 + lane];
    const float bs = bias[lane], gm = gamma[lane], bt = beta[lane];
    const int waves = gridDim.x * 4;
    for (int n = blockIdx.x * 4 + wid; n < N_NODES; n += waves) {
        float xv = x[(size_t)n * 64 + lane];
        const int xbv = __float_as_int(xv);
        float slv = bs;
#pragma unroll
        for (int i = 0; i < 64; ++i) {
            const float s = __int_as_float(__builtin_amdgcn_readlane(xbv, i));
            slv = fmaf(s, wreg[i], slv);
        }
        float v = out[(size_t)n * 64 + lane] + slv;
        v = (v >= 0.f) ? v : 0.1f * v;
        float s1 = v;
#pragma unroll
        for (int mm = 32; mm >= 1; mm >>= 1) s1 += __shfl_xor(s1, mm, 64);
        const float mu = s1 * (1.f / 64.f);
        const float dv = v - mu;
        float s2 = dv * dv;
#pragma unroll
        for (int mm = 32; mm >= 1; mm >>= 1) s2 += __shfl_xor(s2, mm, 64);
        const float var = s2 * (1.f / 64.f);
        out[(size_t)n * 64 + lane] = dv * rsqrtf(var + LN_EPS) * gm + bt;
    }
}

// ---------------------------------------------------------------------------
extern "C" void kernel_launch(void* const* d_in, const int* in_sizes, int n_in,
                              void* d_out, int out_size, void* d_ws, size_t ws_size,
                              hipStream_t stream) {
    const float* x     = (const float*)d_in[0];
    const float* bases = (const float*)d_in[1];
    const float* comp  = (const float*)d_in[2];
    const float* loopw = (const float*)d_in[3];
    const float* bias  = (const float*)d_in[4];
    const float* gamma = (const float*)d_in[5];
    const float* beta  = (const float*)d_in[6];
    const int*   src   = (const int*)d_in[7];
    const int*   dst   = (const int*)d_in[8];
    const int*   et    = (const int*)d_in[9];
    float* out = (float*)d_out;

    size_t p = 0;
    auto alloc = [&](size_t bytes) {
        size_t cur = p;
        p = (p + bytes + 255) & ~(size_t)255;
        return cur;
    };
    char* ws = (char*)d_ws;
    const size_t o_counts = alloc((size_t)NBINS * sizeof(u32));            // 0.4 MB
    const size_t o_wf     = alloc((size_t)4 * 10 * 64 * 8 * sizeof(u16));  // 40 KB
    const size_t o_xb     = alloc((size_t)N_NODES * 64 * sizeof(u16));     // 12.8 MB
    const size_t o_y      = alloc((size_t)N_NODES * 256 * sizeof(u16));    // 51.2 MB
    const size_t o_se     = alloc((size_t)N_EDGES * sizeof(u32));          // 6.4 MB
    const size_t o_priv   = alloc((size_t)NG * NS * RANGE * sizeof(u32));  // 12.8 MB
    const size_t o_offs   = alloc((size_t)NBINS * sizeof(u32));
    const size_t o_bsums  = alloc(128 * sizeof(u32));
    const size_t o_boffs  = alloc(128 * sizeof(u32));
    const size_t o_packed = alloc((size_t)N_EDGES * sizeof(u32));          // 6.4 MB
    const size_t need = p;

    if (ws_size >= need) {
        u32* counts = (u32*)(ws + o_counts);
        u16* wfp    = (u16*)(ws + o_wf);
        u16* xb     = (u16*)(ws + o_xb);
        u16* y      = (u16*)(ws + o_y);
        u32* se     = (u32*)(ws + o_se);
        u32* priv   = (u32*)(ws + o_priv);
        u32* offs   = (u32*)(ws + o_offs);
        u32* bsums  = (u32*)(ws + o_bsums);
        u32* boffs  = (u32*)(ws + o_boffs);
        u32* packed = (u32*)(ws + o_packed);

        k_prep<<<1 + XB_BLOCKS + SE_BLOCKS, 256, 0, stream>>>(
            x, bases, loopw, src, et, wfp, xb, se);
        k_hist<<<NG * NS, 256, 0, stream>>>(dst, priv);
        const int scan_blocks = (NBINS + 1023) / 1024;  // 98
        k_scan_block<<<scan_blocks, 1024, 0, stream>>>(priv, counts, offs, bsums);
        k_scan_sums<<<1, 128, 0, stream>>>(bsums, boffs, scan_blocks);
        k_offs_final<<<(NBINS + 255) / 256, 256, 0, stream>>>(offs, boffs);
        k_scatter<<<NG * NS, 256, 0, stream>>>(dst, se, priv, boffs, packed);
        k_agg<<<2048, 256, 0, stream>>>(xb, (const float4*)comp, packed,
                                        offs, counts, (uint2*)y);
        k_gemm_ln<<<(N_NODES / 16 + 3) / 4, 256, 0, stream>>>(
            (const short8*)y, (const short8*)xb, (const short8*)wfp,
            bias, gamma, beta, out);
    } else {
        hipMemsetAsync(d_out, 0, (size_t)N_NODES * 64 * sizeof(float), stream);
        k_edge_direct<<<(N_EDGES + 3) / 4, 256, 0, stream>>>(
            x, bases, comp, src, dst, et, out);
        k_finalize<<<2048, 256, 0, stream>>>(x, loopw, bias, gamma, beta, out);
    }
}